// Round 11
// baseline (695.454 us; speedup 1.0000x reference)
//
#include <hip/hip_runtime.h>
#include <hip/hip_fp16.h>

#define N_NODES 50000
#define N_EDGES 800000
#define NBINS   391          // ceil(50000/128), 128 dst nodes per bin
#define EPB     4096         // edges per block (bhist / binA)
#define NBLK_E  ((N_EDGES + EPB - 1) / EPB)
#define NTILE   391          // ceil(50000/128) node tiles for pre kernels
#define LSTRIDE 129          // LDS [ch][node] stride, conflict-free
#define CSTRIDE 257          // k_cls LDS stride (256-node tile)

// ---------------- bin-level histogram ----------------
__global__ void k_bhist(const int* __restrict__ dst, int* __restrict__ bincnt) {
    __shared__ int cnt[NBINS];
    int t = threadIdx.x;
    for (int i = t; i < NBINS; i += 256) cnt[i] = 0;
    __syncthreads();
    int base = blockIdx.x * EPB;
    int nE = min(EPB, N_EDGES - base);
    for (int i = t; i < nE; i += 256) atomicAdd(&cnt[dst[base + i] >> 7], 1);
    __syncthreads();
    for (int i = t; i < NBINS; i += 256) if (cnt[i]) atomicAdd(&bincnt[i], cnt[i]);
}

// ---------------- exclusive scan of bin counts ----------------
__global__ void k_bscan(const int* __restrict__ bincnt, int* __restrict__ binoff,
                        int* __restrict__ bincur) {
    __shared__ int tmp[512];
    int t = threadIdx.x;
    int v = (t < NBINS) ? bincnt[t] : 0;
    tmp[t] = v;
    __syncthreads();
    int val = v;
    for (int d = 1; d < 512; d <<= 1) {
        int add = (t >= d) ? tmp[t - d] : 0;
        __syncthreads();
        val += add;
        tmp[t] = val;
        __syncthreads();
    }
    if (t < NBINS) { binoff[t] = val - v; bincur[t] = val - v; }
    if (t == NBINS - 1) binoff[NBINS] = val;
}

// ---------------- pass A: LDS-staged bin scatter (unsorted within bin) ----------------
__global__ void k_binA(const int* __restrict__ src, const int* __restrict__ dst,
                       int* __restrict__ bincur, int* __restrict__ binned) {
    __shared__ int cnt[NBINS];
    __shared__ int sc[512];
    __shared__ int lpos[NBINS];
    __shared__ int base[NBINS];
    __shared__ int stage[EPB];
    __shared__ unsigned short sbin[EPB];
    int t = threadIdx.x;
    int blkbase = blockIdx.x * EPB;
    int nE = min(EPB, N_EDGES - blkbase);
    for (int i = t; i < NBINS; i += 256) cnt[i] = 0;
    __syncthreads();
    int sv[16], dv[16];
#pragma unroll
    for (int k = 0; k < 16; ++k) {
        int e = blkbase + t + k * 256;
        if (e < N_EDGES) {
            sv[k] = src[e];
            dv[k] = dst[e];
            atomicAdd(&cnt[dv[k] >> 7], 1);
        } else dv[k] = -1;
    }
    __syncthreads();
    sc[t]       = (t < NBINS) ? cnt[t] : 0;
    sc[t + 256] = (t + 256 < NBINS) ? cnt[t + 256] : 0;
    __syncthreads();
    for (int d = 1; d < 512; d <<= 1) {
        int s0 = t, s1 = t + 256;
        int n0 = sc[s0] + ((s0 >= d) ? sc[s0 - d] : 0);
        int n1 = sc[s1] + ((s1 >= d) ? sc[s1 - d] : 0);
        __syncthreads();
        sc[s0] = n0; sc[s1] = n1;
        __syncthreads();
    }
    for (int b = t; b < NBINS; b += 256) {
        int excl = sc[b] - cnt[b];
        lpos[b] = excl;
        sc[b] = excl;
        if (cnt[b] > 0) base[b] = atomicAdd(&bincur[b], cnt[b]);
    }
    __syncthreads();
#pragma unroll
    for (int k = 0; k < 16; ++k) {
        if (dv[k] >= 0) {
            int b = dv[k] >> 7;
            int p = atomicAdd(&lpos[b], 1);
            stage[p] = (sv[k] & 0xFFFF) | ((dv[k] & 127) << 16);
            sbin[p] = (unsigned short)b;
        }
    }
    __syncthreads();
    for (int i = t; i < nE; i += 256) {
        int b = sbin[i];
        binned[base[b] + (i - sc[b])] = stage[i];
    }
}

// ---------------- pre1: p = x@w1l (fp16), q = x@w1r + b1 (fp32) ----------------
__global__ __launch_bounds__(512) void k_pre1(const float* __restrict__ x,
                                              const float* __restrict__ wl,
                                              const float* __restrict__ wr,
                                              const float* __restrict__ b,
                                              __half* __restrict__ ph,
                                              float* __restrict__ q) {
    __shared__ float sx[64 * LSTRIDE];
    int t = threadIdx.x;
    int g0 = blockIdx.x * 128;
#pragma unroll
    for (int i = 0; i < 4; ++i) {
        int f = t + i * 512;
        int nd = f >> 4, cq = f & 15;
        int gn = g0 + nd;
        float4 v = (gn < N_NODES) ? ((const float4*)x)[(size_t)gn * 16 + cq]
                                  : make_float4(0.f, 0.f, 0.f, 0.f);
        sx[(cq * 4 + 0) * LSTRIDE + nd] = v.x;
        sx[(cq * 4 + 1) * LSTRIDE + nd] = v.y;
        sx[(cq * 4 + 2) * LSTRIDE + nd] = v.z;
        sx[(cq * 4 + 3) * LSTRIDE + nd] = v.w;
    }
    __syncthreads();
    int role = __builtin_amdgcn_readfirstlane(t >> 7);
    int wsel = role >> 1;
    int c0 = (role & 1) * 32;
    int ln = t & 127;
    int node = g0 + ln;
    const float* __restrict__ wm = wsel ? wr : wl;
    float acc[32];
    if (wsel) {
#pragma unroll
        for (int c = 0; c < 32; ++c) acc[c] = b[c0 + c];
    } else {
#pragma unroll
        for (int c = 0; c < 32; ++c) acc[c] = 0.f;
    }
#pragma unroll
    for (int k = 0; k < 64; ++k) {
        float xk = sx[k * LSTRIDE + ln];
#pragma unroll
        for (int c = 0; c < 32; ++c)
            acc[c] = fmaf(xk, wm[k * 64 + c0 + c], acc[c]);
    }
    if (node >= N_NODES) return;
    if (wsel == 0) {
        alignas(16) __half2 hv[16];
#pragma unroll
        for (int i = 0; i < 16; ++i)
            hv[i] = __floats2half2_rn(acc[2 * i], acc[2 * i + 1]);
        float4* op = (float4*)(ph + (size_t)node * 64 + c0);
#pragma unroll
        for (int i = 0; i < 4; ++i) op[i] = ((float4*)hv)[i];
    } else {
        float4* op = (float4*)(q + (size_t)node * 64 + c0);
#pragma unroll
        for (int i = 0; i < 8; ++i)
            op[i] = make_float4(acc[4 * i], acc[4 * i + 1], acc[4 * i + 2], acc[4 * i + 3]);
    }
}

// ---------------- agg1: bin-owned LDS accumulator, streamed unsorted edges ----------------
// block owns bin (128 dst nodes); per edge: coalesced 128B row load + ds_add_f32
// (bank = lane%32, 2 lanes/bank = conflict-free). No per-node sort needed.
__global__ __launch_bounds__(512) void k_agg1(const int* __restrict__ binoff,
                                              const int* __restrict__ binned,
                                              const __half* __restrict__ ph,
                                              const float* __restrict__ q,
                                              float* __restrict__ h1) {
    __shared__ float acc[128 * 64];   // 32 KB
    __shared__ int sdeg[128];
    int t = threadIdx.x, wv = t >> 6, lane = t & 63;
    for (int i = t; i < 2048; i += 512) ((float4*)acc)[i] = make_float4(0.f, 0.f, 0.f, 0.f);
    if (t < 128) sdeg[t] = 0;
    __syncthreads();
    int b = blockIdx.x;
    int seg0 = binoff[b], seg1 = binoff[b + 1];
    int n = seg1 - seg0;
    int chunk = (n + 7) >> 3;
    int c0 = seg0 + wv * chunk;
    int c1 = min(c0 + chunk, seg1);
    int i = c0;
    for (; i + 3 < c1; i += 4) {
        int e0 = binned[i], e1 = binned[i + 1], e2 = binned[i + 2], e3 = binned[i + 3];
        float v0 = __half2float(ph[(size_t)(e0 & 0xFFFF) * 64 + lane]);
        float v1 = __half2float(ph[(size_t)(e1 & 0xFFFF) * 64 + lane]);
        float v2 = __half2float(ph[(size_t)(e2 & 0xFFFF) * 64 + lane]);
        float v3 = __half2float(ph[(size_t)(e3 & 0xFFFF) * 64 + lane]);
        atomicAdd(&acc[(e0 >> 16) * 64 + lane], v0);
        atomicAdd(&acc[(e1 >> 16) * 64 + lane], v1);
        atomicAdd(&acc[(e2 >> 16) * 64 + lane], v2);
        atomicAdd(&acc[(e3 >> 16) * 64 + lane], v3);
        if (lane == 0) {
            atomicAdd(&sdeg[e0 >> 16], 1);
            atomicAdd(&sdeg[e1 >> 16], 1);
            atomicAdd(&sdeg[e2 >> 16], 1);
            atomicAdd(&sdeg[e3 >> 16], 1);
        }
    }
    for (; i < c1; ++i) {
        int e = binned[i];
        float v = __half2float(ph[(size_t)(e & 0xFFFF) * 64 + lane]);
        atomicAdd(&acc[(e >> 16) * 64 + lane], v);
        if (lane == 0) atomicAdd(&sdeg[e >> 16], 1);
    }
    __syncthreads();
    int n0 = b << 7;
    for (int nn = wv; nn < 128; nn += 8) {
        int node = n0 + nn;
        if (node < N_NODES) {
            float inv = 1.0f / fmaxf((float)sdeg[nn], 1.0f);
            float val = fmaf(acc[nn * 64 + lane], inv, q[(size_t)node * 64 + lane]);
            h1[(size_t)node * 64 + lane] = fmaxf(val, 0.0f);
        }
    }
}

// ---------------- pre2: z = h1@w2l (fp16), r = h1@w2r + b2 (fp32) ----------------
__global__ __launch_bounds__(256) void k_pre2(const float* __restrict__ h1,
                                              const float* __restrict__ w2l,
                                              const float* __restrict__ w2r,
                                              const float* __restrict__ b2,
                                              __half* __restrict__ zh,
                                              float* __restrict__ r) {
    __shared__ float sx[64 * LSTRIDE];
    int t = threadIdx.x;
    int g0 = blockIdx.x * 128;
#pragma unroll
    for (int i = 0; i < 8; ++i) {
        int f = t + i * 256;
        int nd = f >> 4, cq = f & 15;
        int gn = g0 + nd;
        float4 v = (gn < N_NODES) ? ((const float4*)h1)[(size_t)gn * 16 + cq]
                                  : make_float4(0.f, 0.f, 0.f, 0.f);
        sx[(cq * 4 + 0) * LSTRIDE + nd] = v.x;
        sx[(cq * 4 + 1) * LSTRIDE + nd] = v.y;
        sx[(cq * 4 + 2) * LSTRIDE + nd] = v.z;
        sx[(cq * 4 + 3) * LSTRIDE + nd] = v.w;
    }
    __syncthreads();
    int role = __builtin_amdgcn_readfirstlane(t >> 7);
    int ln = t & 127;
    int node = g0 + ln;
    const float* __restrict__ wm = role ? w2r : w2l;
    float acc[32];
    if (role) {
#pragma unroll
        for (int c = 0; c < 32; ++c) acc[c] = b2[c];
    } else {
#pragma unroll
        for (int c = 0; c < 32; ++c) acc[c] = 0.f;
    }
#pragma unroll
    for (int k = 0; k < 64; ++k) {
        float xk = sx[k * LSTRIDE + ln];
#pragma unroll
        for (int c = 0; c < 32; ++c)
            acc[c] = fmaf(xk, wm[k * 32 + c], acc[c]);
    }
    if (node >= N_NODES) return;
    if (role == 0) {
        alignas(16) __half2 hv[16];
#pragma unroll
        for (int i = 0; i < 16; ++i)
            hv[i] = __floats2half2_rn(acc[2 * i], acc[2 * i + 1]);
        float4* op = (float4*)(zh + (size_t)node * 32);
#pragma unroll
        for (int i = 0; i < 4; ++i) op[i] = ((float4*)hv)[i];
    } else {
        float4* op = (float4*)(r + (size_t)node * 32);
#pragma unroll
        for (int i = 0; i < 8; ++i)
            op[i] = make_float4(acc[4 * i], acc[4 * i + 1], acc[4 * i + 2], acc[4 * i + 3]);
    }
}

// ---------------- agg2: bin-owned LDS accumulator, 2 edges per wave ----------------
__global__ __launch_bounds__(512) void k_agg2(const int* __restrict__ binoff,
                                              const int* __restrict__ binned,
                                              const __half* __restrict__ zh,
                                              const float* __restrict__ r,
                                              float* __restrict__ h2) {
    __shared__ float acc[128 * 32];   // 16 KB
    __shared__ int sdeg[128];
    int t = threadIdx.x, wv = t >> 6;
    int half = (t >> 5) & 1, l32 = t & 31;
    for (int i = t; i < 1024; i += 512) ((float4*)acc)[i] = make_float4(0.f, 0.f, 0.f, 0.f);
    if (t < 128) sdeg[t] = 0;
    __syncthreads();
    int b = blockIdx.x;
    int seg0 = binoff[b], seg1 = binoff[b + 1];
    int n = seg1 - seg0;
    int chunk = (n + 7) >> 3;
    int c0 = seg0 + wv * chunk;
    int c1 = min(c0 + chunk, seg1);
    for (int i = c0; i < c1; i += 4) {
        int iA = i + half, iB = i + 2 + half;
        if (iA < c1) {
            int e = binned[iA];
            float v = __half2float(zh[(size_t)(e & 0xFFFF) * 32 + l32]);
            atomicAdd(&acc[(e >> 16) * 32 + l32], v);
            if (l32 == 0) atomicAdd(&sdeg[e >> 16], 1);
        }
        if (iB < c1) {
            int e = binned[iB];
            float v = __half2float(zh[(size_t)(e & 0xFFFF) * 32 + l32]);
            atomicAdd(&acc[(e >> 16) * 32 + l32], v);
            if (l32 == 0) atomicAdd(&sdeg[e >> 16], 1);
        }
    }
    __syncthreads();
    int n0 = b << 7;
    int nloc = t >> 5;                 // 0..15
#pragma unroll
    for (int k = 0; k < 8; ++k) {
        int nn = nloc + 16 * k;
        int node = n0 + nn;
        if (node < N_NODES) {
            float inv = 1.0f / fmaxf((float)sdeg[nn], 1.0f);
            float val = fmaf(acc[nn * 32 + l32], inv, r[(size_t)node * 32 + l32]);
            h2[(size_t)node * 32 + l32] = fmaxf(val, 0.0f);
        }
    }
}

// ---------------- cls: out = relu(h2@wc1 + bc1)@wc2 + bc2 ----------------
__global__ __launch_bounds__(256) void k_cls(const float* __restrict__ h2,
                                             const float* __restrict__ wc1,
                                             const float* __restrict__ bc1,
                                             const float* __restrict__ wc2,
                                             const float* __restrict__ bc2,
                                             float* __restrict__ out) {
    __shared__ float sh[32 * CSTRIDE];
    int t = threadIdx.x;
    int g0 = blockIdx.x * 256;
#pragma unroll
    for (int i = 0; i < 8; ++i) {
        int f = t + i * 256;
        int nd = f >> 3, cq = f & 7;
        int gn = g0 + nd;
        float4 v = (gn < N_NODES) ? ((const float4*)h2)[(size_t)gn * 8 + cq]
                                  : make_float4(0.f, 0.f, 0.f, 0.f);
        sh[(cq * 4 + 0) * CSTRIDE + nd] = v.x;
        sh[(cq * 4 + 1) * CSTRIDE + nd] = v.y;
        sh[(cq * 4 + 2) * CSTRIDE + nd] = v.z;
        sh[(cq * 4 + 3) * CSTRIDE + nd] = v.w;
    }
    __syncthreads();
    int node = g0 + t;
    float acc[16];
#pragma unroll
    for (int j = 0; j < 16; ++j) acc[j] = bc1[j];
#pragma unroll
    for (int k = 0; k < 32; ++k) {
        float xk = sh[k * CSTRIDE + t];
#pragma unroll
        for (int j = 0; j < 16; ++j)
            acc[j] = fmaf(xk, wc1[k * 16 + j], acc[j]);
    }
    float o0 = bc2[0], o1 = bc2[1];
#pragma unroll
    for (int j = 0; j < 16; ++j) {
        float aj = fmaxf(acc[j], 0.f);
        o0 = fmaf(aj, wc2[j * 2 + 0], o0);
        o1 = fmaf(aj, wc2[j * 2 + 1], o1);
    }
    if (node < N_NODES)
        *(float2*)(out + (size_t)node * 2) = make_float2(o0, o1);
}

extern "C" void kernel_launch(void* const* d_in, const int* in_sizes, int n_in,
                              void* d_out, int out_size, void* d_ws, size_t ws_size,
                              hipStream_t stream) {
    const float* x   = (const float*)d_in[0];
    const int*   ei  = (const int*)d_in[1];
    const int*   src = ei;
    const int*   dst = ei + N_EDGES;
    const float* w1l = (const float*)d_in[2];
    const float* w1r = (const float*)d_in[3];
    const float* b1  = (const float*)d_in[4];
    const float* w2l = (const float*)d_in[5];
    const float* w2r = (const float*)d_in[6];
    const float* b2  = (const float*)d_in[7];
    const float* wc1 = (const float*)d_in[8];
    const float* bc1 = (const float*)d_in[9];
    const float* wc2 = (const float*)d_in[10];
    const float* bc2 = (const float*)d_in[11];
    float* out = (float*)d_out;

    // ws layout (4B units):
    //   bincnt[400] | binoff[400] | bincur[400] | binned[E]
    //   | h1[64N] (reused as h2) | q[64N] (zh[16N]+r[32N] overlay) | ph[32N halfs]
    int*   wi     = (int*)d_ws;
    int*   bincnt = wi;
    int*   binoff = wi + 400;
    int*   bincur = wi + 800;
    int*   binned = wi + 1200;
    float* h1     = (float*)(binned + N_EDGES);
    float* q      = h1 + (size_t)64 * N_NODES;
    float* phf    = q + (size_t)64 * N_NODES;
    __half* ph    = (__half*)phf;
    __half* zh    = (__half*)q;                       // overlay: q dead after agg1
    float*  r     = q + (size_t)16 * N_NODES;
    float*  h2    = h1;                               // h1 dead after pre2

    // ---- bin-grouped edge list ----
    hipMemsetAsync(bincnt, 0, 400 * sizeof(int), stream);
    k_bhist<<<NBLK_E, 256, 0, stream>>>(dst, bincnt);
    k_bscan<<<1, 512, 0, stream>>>(bincnt, binoff, bincur);
    k_binA<<<NBLK_E, 256, 0, stream>>>(src, dst, bincur, binned);

    // ---- layer 1 ----
    k_pre1<<<NTILE, 512, 0, stream>>>(x, w1l, w1r, b1, ph, q);
    k_agg1<<<NBINS, 512, 0, stream>>>(binoff, binned, ph, q, h1);

    // ---- layer 2 ----
    k_pre2<<<NTILE, 256, 0, stream>>>(h1, w2l, w2r, b2, zh, r);
    k_agg2<<<NBINS, 512, 0, stream>>>(binoff, binned, zh, r, h2);

    // ---- classifier ----
    k_cls<<<(N_NODES + 255) / 256, 256, 0, stream>>>(h2, wc1, bc1, wc2, bc2, out);
}

// Round 12
// 197.308 us; speedup vs baseline: 3.5247x; 3.5247x over previous
//
#include <hip/hip_runtime.h>
#include <hip/hip_fp16.h>

#define N_NODES 50000
#define N_EDGES 800000
#define NBINS   391          // ceil(50000/128), 128 dst nodes per bin
#define EPB     4096         // edges per block (bhist / binA)
#define NBLK_E  ((N_EDGES + EPB - 1) / EPB)
#define MAXSEG  4096         // pass-B LDS segment capacity (mean 2046)
#define NTILE   391          // ceil(50000/128) node tiles for pre kernels
#define LSTRIDE 129          // LDS [ch][node] stride, conflict-free

// ---------------- bin-level histogram ----------------
__global__ void k_bhist(const int* __restrict__ dst, int* __restrict__ bincnt) {
    __shared__ int cnt[NBINS];
    int t = threadIdx.x;
    for (int i = t; i < NBINS; i += 256) cnt[i] = 0;
    __syncthreads();
    int base = blockIdx.x * EPB;
    int nE = min(EPB, N_EDGES - base);
    for (int i = t; i < nE; i += 256) atomicAdd(&cnt[dst[base + i] >> 7], 1);
    __syncthreads();
    for (int i = t; i < NBINS; i += 256) if (cnt[i]) atomicAdd(&bincnt[i], cnt[i]);
}

// ---------------- exclusive scan of bin counts ----------------
__global__ void k_bscan(const int* __restrict__ bincnt, int* __restrict__ binoff,
                        int* __restrict__ bincur) {
    __shared__ int tmp[512];
    int t = threadIdx.x;
    int v = (t < NBINS) ? bincnt[t] : 0;
    tmp[t] = v;
    __syncthreads();
    int val = v;
    for (int d = 1; d < 512; d <<= 1) {
        int add = (t >= d) ? tmp[t - d] : 0;
        __syncthreads();
        val += add;
        tmp[t] = val;
        __syncthreads();
    }
    if (t < NBINS) { binoff[t] = val - v; bincur[t] = val - v; }
    if (t == NBINS - 1) binoff[NBINS] = val;
}

// ---------------- pass A: LDS-staged bin scatter ----------------
__global__ void k_binA(const int* __restrict__ src, const int* __restrict__ dst,
                       int* __restrict__ bincur, int* __restrict__ binned) {
    __shared__ int cnt[NBINS];
    __shared__ int sc[512];
    __shared__ int lpos[NBINS];
    __shared__ int base[NBINS];
    __shared__ int stage[EPB];
    __shared__ unsigned short sbin[EPB];
    int t = threadIdx.x;
    int blkbase = blockIdx.x * EPB;
    int nE = min(EPB, N_EDGES - blkbase);
    for (int i = t; i < NBINS; i += 256) cnt[i] = 0;
    __syncthreads();
    int sv[16], dv[16];
#pragma unroll
    for (int k = 0; k < 16; ++k) {
        int e = blkbase + t + k * 256;
        if (e < N_EDGES) {
            sv[k] = src[e];
            dv[k] = dst[e];
            atomicAdd(&cnt[dv[k] >> 7], 1);
        } else dv[k] = -1;
    }
    __syncthreads();
    sc[t]       = (t < NBINS) ? cnt[t] : 0;
    sc[t + 256] = (t + 256 < NBINS) ? cnt[t + 256] : 0;
    __syncthreads();
    for (int d = 1; d < 512; d <<= 1) {
        int s0 = t, s1 = t + 256;
        int n0 = sc[s0] + ((s0 >= d) ? sc[s0 - d] : 0);
        int n1 = sc[s1] + ((s1 >= d) ? sc[s1 - d] : 0);
        __syncthreads();
        sc[s0] = n0; sc[s1] = n1;
        __syncthreads();
    }
    for (int b = t; b < NBINS; b += 256) {
        int excl = sc[b] - cnt[b];
        lpos[b] = excl;
        sc[b] = excl;
        if (cnt[b] > 0) base[b] = atomicAdd(&bincur[b], cnt[b]);
    }
    __syncthreads();
#pragma unroll
    for (int k = 0; k < 16; ++k) {
        if (dv[k] >= 0) {
            int b = dv[k] >> 7;
            int p = atomicAdd(&lpos[b], 1);
            stage[p] = (sv[k] & 0xFFFF) | ((dv[k] & 127) << 16);
            sbin[p] = (unsigned short)b;
        }
    }
    __syncthreads();
    for (int i = t; i < nE; i += 256) {
        int b = sbin[i];
        binned[base[b] + (i - sc[b])] = stage[i];
    }
}

// ---------------- pass B: per-bin counting sort; derives off[] ----------------
__global__ void k_binB(const int* __restrict__ binoff, const int* __restrict__ binned,
                       int* __restrict__ off, int* __restrict__ esrc) {
    __shared__ int cnt[128];
    __shared__ int tmp[128];
    __shared__ int cur[128];
    __shared__ int buf[MAXSEG];
    int b = blockIdx.x, t = threadIdx.x;
    int n0 = b << 7;
    int seg0 = binoff[b], seg1 = binoff[b + 1];
    int n = seg1 - seg0;
    if (t < 128) cnt[t] = 0;
    __syncthreads();
    for (int i = t; i < n; i += 256) atomicAdd(&cnt[binned[seg0 + i] >> 16], 1);
    __syncthreads();
    int v = (t < 128) ? cnt[t] : 0;
    if (t < 128) tmp[t] = v;
    __syncthreads();
    int val = v;
    for (int d = 1; d < 128; d <<= 1) {
        int add = (t >= d && t < 128) ? tmp[t - d] : 0;
        __syncthreads();
        if (t < 128) { val += add; tmp[t] = val; }
        __syncthreads();
    }
    if (t < 128) {
        int excl = val - v;
        cur[t] = excl;
        int node = n0 + t;
        if (node < N_NODES) off[node] = seg0 + excl;
    }
    __syncthreads();
    if (n <= MAXSEG) {
        for (int i = t; i < n; i += 256) {
            int w = binned[seg0 + i];
            int p = atomicAdd(&cur[w >> 16], 1);
            buf[p] = w & 0xFFFF;
        }
        __syncthreads();
        for (int i = t; i < n; i += 256) esrc[seg0 + i] = buf[i];
    } else {
        for (int i = t; i < n; i += 256) {
            int w = binned[seg0 + i];
            int p = atomicAdd(&cur[w >> 16], 1);
            esrc[seg0 + p] = w & 0xFFFF;
        }
    }
}

// ---------------- pre1: p = x@w1l (fp16), q = x@w1r + b1 (fp32) ----------------
__global__ __launch_bounds__(512) void k_pre1(const float* __restrict__ x,
                                              const float* __restrict__ wl,
                                              const float* __restrict__ wr,
                                              const float* __restrict__ b,
                                              __half* __restrict__ ph,
                                              float* __restrict__ q) {
    __shared__ float sx[64 * LSTRIDE];
    int t = threadIdx.x;
    int g0 = blockIdx.x * 128;
#pragma unroll
    for (int i = 0; i < 4; ++i) {
        int f = t + i * 512;
        int nd = f >> 4, cq = f & 15;
        int gn = g0 + nd;
        float4 v = (gn < N_NODES) ? ((const float4*)x)[(size_t)gn * 16 + cq]
                                  : make_float4(0.f, 0.f, 0.f, 0.f);
        sx[(cq * 4 + 0) * LSTRIDE + nd] = v.x;
        sx[(cq * 4 + 1) * LSTRIDE + nd] = v.y;
        sx[(cq * 4 + 2) * LSTRIDE + nd] = v.z;
        sx[(cq * 4 + 3) * LSTRIDE + nd] = v.w;
    }
    __syncthreads();
    int role = __builtin_amdgcn_readfirstlane(t >> 7);
    int wsel = role >> 1;
    int c0 = (role & 1) * 32;
    int ln = t & 127;
    int node = g0 + ln;
    const float* __restrict__ wm = wsel ? wr : wl;
    float acc[32];
    if (wsel) {
#pragma unroll
        for (int c = 0; c < 32; ++c) acc[c] = b[c0 + c];
    } else {
#pragma unroll
        for (int c = 0; c < 32; ++c) acc[c] = 0.f;
    }
#pragma unroll
    for (int k = 0; k < 64; ++k) {
        float xk = sx[k * LSTRIDE + ln];
#pragma unroll
        for (int c = 0; c < 32; ++c)
            acc[c] = fmaf(xk, wm[k * 64 + c0 + c], acc[c]);
    }
    if (node >= N_NODES) return;
    if (wsel == 0) {
        alignas(16) __half2 hv[16];
#pragma unroll
        for (int i = 0; i < 16; ++i)
            hv[i] = __floats2half2_rn(acc[2 * i], acc[2 * i + 1]);
        float4* op = (float4*)(ph + (size_t)node * 64 + c0);
#pragma unroll
        for (int i = 0; i < 4; ++i) op[i] = ((float4*)hv)[i];
    } else {
        float4* op = (float4*)(q + (size_t)node * 64 + c0);
#pragma unroll
        for (int i = 0; i < 8; ++i)
            op[i] = make_float4(acc[4 * i], acc[4 * i + 1], acc[4 * i + 2], acc[4 * i + 3]);
    }
}

// dequant-accumulate 16B of halfs into 8 fp32 accs
__device__ __forceinline__ void acc8(float* a, float4 rv) {
    const __half2* hp = (const __half2*)&rv;
    float2 f0 = __half22float2(hp[0]), f1 = __half22float2(hp[1]);
    float2 f2 = __half22float2(hp[2]), f3 = __half22float2(hp[3]);
    a[0] += f0.x; a[1] += f0.y; a[2] += f1.x; a[3] += f1.y;
    a[4] += f2.x; a[5] += f2.y; a[6] += f3.x; a[7] += f3.y;
}

// ---------------- agg1: h1 = relu(mean-gather(p) + q) ----------------
// half-wave (32 lanes) per node: eg = 0..3 edge slots, cg = 0..7 16B groups.
__global__ __launch_bounds__(256) void k_agg1(const int* __restrict__ off,
                                              const int* __restrict__ esrc,
                                              const __half* __restrict__ ph,
                                              const float* __restrict__ q,
                                              float* __restrict__ h1) {
    int wv = threadIdx.x >> 6, lane = threadIdx.x & 63;
    int h = lane >> 5, l32 = lane & 31;
    int node = blockIdx.x * 8 + wv * 2 + h;  // N % 8 == 0
    int eg = l32 >> 3;                        // 0..3
    int cg = l32 & 7;                         // 16B group: halfs cg*8..cg*8+7
    int s0 = off[node];
    int s1 = (node == N_NODES - 1) ? N_EDGES : off[node + 1];
    float a[8] = {0, 0, 0, 0, 0, 0, 0, 0};
    float c2[8] = {0, 0, 0, 0, 0, 0, 0, 0};
    for (int i = s0; i < s1; i += 8) {
        int i0 = i + eg, i1 = i + 4 + eg;
        if (i0 < s1) acc8(a,  *(const float4*)(ph + (size_t)esrc[i0] * 64 + (cg << 3)));
        if (i1 < s1) acc8(c2, *(const float4*)(ph + (size_t)esrc[i1] * 64 + (cg << 3)));
    }
#pragma unroll
    for (int j = 0; j < 8; ++j) a[j] += c2[j];
#pragma unroll
    for (int j = 0; j < 8; ++j) {
        a[j] += __shfl_xor(a[j], 8);
        a[j] += __shfl_xor(a[j], 16);
    }
    if (eg == 0) {
        float inv = 1.0f / fmaxf((float)(s1 - s0), 1.0f);
        const float4* qp = (const float4*)(q + (size_t)node * 64 + (cg << 3));
        float4 q0 = qp[0], q1 = qp[1];
        float4 o0, o1;
        o0.x = fmaxf(fmaf(a[0], inv, q0.x), 0.f);
        o0.y = fmaxf(fmaf(a[1], inv, q0.y), 0.f);
        o0.z = fmaxf(fmaf(a[2], inv, q0.z), 0.f);
        o0.w = fmaxf(fmaf(a[3], inv, q0.w), 0.f);
        o1.x = fmaxf(fmaf(a[4], inv, q1.x), 0.f);
        o1.y = fmaxf(fmaf(a[5], inv, q1.y), 0.f);
        o1.z = fmaxf(fmaf(a[6], inv, q1.z), 0.f);
        o1.w = fmaxf(fmaf(a[7], inv, q1.w), 0.f);
        float4* op = (float4*)(h1 + (size_t)node * 64 + (cg << 3));
        op[0] = o0; op[1] = o1;
    }
}

// ---------------- pre2: z = h1@w2l (fp16), r = h1@w2r + b2 (fp32) ----------------
__global__ __launch_bounds__(256) void k_pre2(const float* __restrict__ h1,
                                              const float* __restrict__ w2l,
                                              const float* __restrict__ w2r,
                                              const float* __restrict__ b2,
                                              __half* __restrict__ zh,
                                              float* __restrict__ r) {
    __shared__ float sx[64 * LSTRIDE];
    int t = threadIdx.x;
    int g0 = blockIdx.x * 128;
#pragma unroll
    for (int i = 0; i < 8; ++i) {
        int f = t + i * 256;
        int nd = f >> 4, cq = f & 15;
        int gn = g0 + nd;
        float4 v = (gn < N_NODES) ? ((const float4*)h1)[(size_t)gn * 16 + cq]
                                  : make_float4(0.f, 0.f, 0.f, 0.f);
        sx[(cq * 4 + 0) * LSTRIDE + nd] = v.x;
        sx[(cq * 4 + 1) * LSTRIDE + nd] = v.y;
        sx[(cq * 4 + 2) * LSTRIDE + nd] = v.z;
        sx[(cq * 4 + 3) * LSTRIDE + nd] = v.w;
    }
    __syncthreads();
    int role = __builtin_amdgcn_readfirstlane(t >> 7);
    int ln = t & 127;
    int node = g0 + ln;
    const float* __restrict__ wm = role ? w2r : w2l;
    float acc[32];
    if (role) {
#pragma unroll
        for (int c = 0; c < 32; ++c) acc[c] = b2[c];
    } else {
#pragma unroll
        for (int c = 0; c < 32; ++c) acc[c] = 0.f;
    }
#pragma unroll
    for (int k = 0; k < 64; ++k) {
        float xk = sx[k * LSTRIDE + ln];
#pragma unroll
        for (int c = 0; c < 32; ++c)
            acc[c] = fmaf(xk, wm[k * 32 + c], acc[c]);
    }
    if (node >= N_NODES) return;
    if (role == 0) {
        alignas(16) __half2 hv[16];
#pragma unroll
        for (int i = 0; i < 16; ++i)
            hv[i] = __floats2half2_rn(acc[2 * i], acc[2 * i + 1]);
        float4* op = (float4*)(zh + (size_t)node * 32);
#pragma unroll
        for (int i = 0; i < 4; ++i) op[i] = ((float4*)hv)[i];
    } else {
        float4* op = (float4*)(r + (size_t)node * 32);
#pragma unroll
        for (int i = 0; i < 8; ++i)
            op[i] = make_float4(acc[4 * i], acc[4 * i + 1], acc[4 * i + 2], acc[4 * i + 3]);
    }
}

// ---------------- agg2 + classifier fused ----------------
// quarter-wave (16 lanes) per node: eg = 0..3 edge slots, cg = 0..3 16B groups.
// Block = 256 thr = 16 nodes; h2 stays in LDS; MLP uses 16 threads/node.
__global__ __launch_bounds__(256) void k_agg2cls(const int* __restrict__ off,
                                                 const int* __restrict__ esrc,
                                                 const __half* __restrict__ zh,
                                                 const float* __restrict__ r,
                                                 const float* __restrict__ wc1,
                                                 const float* __restrict__ bc1,
                                                 const float* __restrict__ wc2,
                                                 const float* __restrict__ bc2,
                                                 float* __restrict__ out) {
    __shared__ float sh2[16 * 33];    // [node][ch], stride 33 (conflict-free)
    __shared__ float sh3[16 * 17];    // [node][j],  stride 17
    __shared__ float swc1[512];
    __shared__ float sbc1[16];
    __shared__ float swc2[32];
    __shared__ float sbc2[2];
    int t = threadIdx.x;
    // stage classifier weights (no sync needed until after sh2 writes)
    swc1[t] = wc1[t];
    swc1[t + 256] = wc1[t + 256];
    if (t < 16) sbc1[t] = bc1[t];
    if (t < 32) swc2[t] = wc2[t];
    if (t < 2)  sbc2[t] = bc2[t];

    int lane = t & 63;
    int l16 = lane & 15;
    int nl = (t >> 4) & 15;                  // node-local 0..15
    int node = blockIdx.x * 16 + nl;         // N % 16 == 0
    int eg = l16 >> 2;                        // 0..3
    int cg = l16 & 3;                         // 16B group: halfs cg*8..cg*8+7
    int s0 = off[node];
    int s1 = (node == N_NODES - 1) ? N_EDGES : off[node + 1];
    float a[8] = {0, 0, 0, 0, 0, 0, 0, 0};
    float c2[8] = {0, 0, 0, 0, 0, 0, 0, 0};
    for (int i = s0; i < s1; i += 8) {
        int i0 = i + eg, i1 = i + 4 + eg;
        if (i0 < s1) acc8(a,  *(const float4*)(zh + (size_t)esrc[i0] * 32 + (cg << 3)));
        if (i1 < s1) acc8(c2, *(const float4*)(zh + (size_t)esrc[i1] * 32 + (cg << 3)));
    }
#pragma unroll
    for (int j = 0; j < 8; ++j) a[j] += c2[j];
#pragma unroll
    for (int j = 0; j < 8; ++j) {
        a[j] += __shfl_xor(a[j], 4);
        a[j] += __shfl_xor(a[j], 8);
    }
    if (eg == 0) {
        float inv = 1.0f / fmaxf((float)(s1 - s0), 1.0f);
        const float4* rp = (const float4*)(r + (size_t)node * 32 + (cg << 3));
        float4 r0 = rp[0], r1 = rp[1];
        float* d = sh2 + nl * 33 + (cg << 3);
        d[0] = fmaxf(fmaf(a[0], inv, r0.x), 0.f);
        d[1] = fmaxf(fmaf(a[1], inv, r0.y), 0.f);
        d[2] = fmaxf(fmaf(a[2], inv, r0.z), 0.f);
        d[3] = fmaxf(fmaf(a[3], inv, r0.w), 0.f);
        d[4] = fmaxf(fmaf(a[4], inv, r1.x), 0.f);
        d[5] = fmaxf(fmaf(a[5], inv, r1.y), 0.f);
        d[6] = fmaxf(fmaf(a[6], inv, r1.z), 0.f);
        d[7] = fmaxf(fmaf(a[7], inv, r1.w), 0.f);
    }
    __syncthreads();
    // MLP1: 16 threads per node, thread j computes h3[j]
    int n = t >> 4, j = t & 15;
    float acc1 = sbc1[j];
#pragma unroll
    for (int k = 0; k < 32; ++k)
        acc1 = fmaf(sh2[n * 33 + k], swc1[k * 16 + j], acc1);
    sh3[n * 17 + j] = fmaxf(acc1, 0.f);
    __syncthreads();
    // MLP2: 1 thread per node
    if (t < 16) {
        int nn = t;
        float o0 = sbc2[0], o1 = sbc2[1];
#pragma unroll
        for (int k = 0; k < 16; ++k) {
            float h3k = sh3[nn * 17 + k];
            o0 = fmaf(h3k, swc2[k * 2 + 0], o0);
            o1 = fmaf(h3k, swc2[k * 2 + 1], o1);
        }
        int gnode = blockIdx.x * 16 + nn;
        *(float2*)(out + (size_t)gnode * 2) = make_float2(o0, o1);
    }
}

extern "C" void kernel_launch(void* const* d_in, const int* in_sizes, int n_in,
                              void* d_out, int out_size, void* d_ws, size_t ws_size,
                              hipStream_t stream) {
    const float* x   = (const float*)d_in[0];
    const int*   ei  = (const int*)d_in[1];
    const int*   src = ei;
    const int*   dst = ei + N_EDGES;
    const float* w1l = (const float*)d_in[2];
    const float* w1r = (const float*)d_in[3];
    const float* b1  = (const float*)d_in[4];
    const float* w2l = (const float*)d_in[5];
    const float* w2r = (const float*)d_in[6];
    const float* b2  = (const float*)d_in[7];
    const float* wc1 = (const float*)d_in[8];
    const float* bc1 = (const float*)d_in[9];
    const float* wc2 = (const float*)d_in[10];
    const float* bc2 = (const float*)d_in[11];
    float* out = (float*)d_out;

    // ws layout (4B units):
    //   bincnt[400] | binoff[400] | bincur[400] | off[N] | binned[E] | esrc[E]
    //   | h1[64N] | q[64N] (zh[16N]+r[32N] overlay) | ph[32N halfs = 16N floats]
    int*   wi     = (int*)d_ws;
    int*   bincnt = wi;
    int*   binoff = wi + 400;
    int*   bincur = wi + 800;
    int*   off    = wi + 1200;
    int*   binned = off + N_NODES;
    int*   esrc   = binned + N_EDGES;
    float* h1     = (float*)(esrc + N_EDGES);
    float* q      = h1 + (size_t)64 * N_NODES;
    float* phf    = q + (size_t)64 * N_NODES;
    __half* ph    = (__half*)phf;
    __half* zh    = (__half*)q;                       // overlay: q dead after agg1
    float*  r     = q + (size_t)16 * N_NODES;

    // ---- CSR build ----
    hipMemsetAsync(bincnt, 0, 400 * sizeof(int), stream);
    k_bhist<<<NBLK_E, 256, 0, stream>>>(dst, bincnt);
    k_bscan<<<1, 512, 0, stream>>>(bincnt, binoff, bincur);
    k_binA<<<NBLK_E, 256, 0, stream>>>(src, dst, bincur, binned);
    k_binB<<<NBINS, 256, 0, stream>>>(binoff, binned, off, esrc);

    // ---- layer 1 ----
    k_pre1<<<NTILE, 512, 0, stream>>>(x, w1l, w1r, b1, ph, q);
    k_agg1<<<N_NODES / 8, 256, 0, stream>>>(off, esrc, ph, q, h1);

    // ---- layer 2 + classifier (fused) ----
    k_pre2<<<NTILE, 256, 0, stream>>>(h1, w2l, w2r, b2, zh, r);
    k_agg2cls<<<N_NODES / 16, 256, 0, stream>>>(off, esrc, zh, r,
                                                wc1, bc1, wc2, bc2, out);
}

// Round 13
// 195.167 us; speedup vs baseline: 3.5634x; 1.0110x over previous
//
#include <hip/hip_runtime.h>
#include <hip/hip_fp16.h>

#define N_NODES 50000
#define N_EDGES 800000
#define NBINS   391          // ceil(50000/128), 128 dst nodes per bin
#define CAP     4096         // fixed per-bin capacity (mean 2048, sigma 45 -> 45σ margin)
#define EPB     4096         // edges per block (binA)
#define NBLK_E  ((N_EDGES + EPB - 1) / EPB)
#define NTILE   391          // ceil(50000/128) node tiles for pre kernels
#define LSTRIDE 129          // LDS [ch][node] stride, conflict-free

// ---------------- pass A: LDS-staged bin scatter (fixed-capacity bins) ----------------
// bin base = b*CAP (static) -> no global histogram/scan pass needed.
__global__ void k_binA(const int* __restrict__ src, const int* __restrict__ dst,
                       int* __restrict__ bincur, int* __restrict__ binned) {
    __shared__ int cnt[NBINS];
    __shared__ int sc[512];
    __shared__ int lpos[NBINS];
    __shared__ int base[NBINS];
    __shared__ int stage[EPB];
    __shared__ unsigned short sbin[EPB];
    int t = threadIdx.x;
    int blkbase = blockIdx.x * EPB;
    int nE = min(EPB, N_EDGES - blkbase);
    for (int i = t; i < NBINS; i += 256) cnt[i] = 0;
    __syncthreads();
    int sv[16], dv[16];
#pragma unroll
    for (int k = 0; k < 16; ++k) {
        int e = blkbase + t + k * 256;
        if (e < N_EDGES) {
            sv[k] = src[e];
            dv[k] = dst[e];
            atomicAdd(&cnt[dv[k] >> 7], 1);
        } else dv[k] = -1;
    }
    __syncthreads();
    sc[t]       = (t < NBINS) ? cnt[t] : 0;
    sc[t + 256] = (t + 256 < NBINS) ? cnt[t + 256] : 0;
    __syncthreads();
    for (int d = 1; d < 512; d <<= 1) {
        int s0 = t, s1 = t + 256;
        int n0 = sc[s0] + ((s0 >= d) ? sc[s0 - d] : 0);
        int n1 = sc[s1] + ((s1 >= d) ? sc[s1 - d] : 0);
        __syncthreads();
        sc[s0] = n0; sc[s1] = n1;
        __syncthreads();
    }
    for (int b = t; b < NBINS; b += 256) {
        int excl = sc[b] - cnt[b];
        lpos[b] = excl;
        sc[b] = excl;
        if (cnt[b] > 0) base[b] = b * CAP + atomicAdd(&bincur[b], cnt[b]);
    }
    __syncthreads();
#pragma unroll
    for (int k = 0; k < 16; ++k) {
        if (dv[k] >= 0) {
            int b = dv[k] >> 7;
            int p = atomicAdd(&lpos[b], 1);
            stage[p] = (sv[k] & 0xFFFF) | ((dv[k] & 127) << 16);
            sbin[p] = (unsigned short)b;
        }
    }
    __syncthreads();
    for (int i = t; i < nE; i += 256) {
        int b = sbin[i];
        int pos = base[b] + (i - sc[b]);
        if (pos < (b + 1) * CAP) binned[pos] = stage[i];   // 45-sigma guard
    }
}

// ---------------- pass B: per-bin counting sort; emits off[] + deg[] ----------------
__global__ void k_binB(const int* __restrict__ bincur, const int* __restrict__ binned,
                       int* __restrict__ off, unsigned short* __restrict__ deg,
                       int* __restrict__ esrc) {
    __shared__ int cnt[128];
    __shared__ int tmp[128];
    __shared__ int cur[128];
    __shared__ int buf[CAP];
    int b = blockIdx.x, t = threadIdx.x;
    int n0 = b << 7;
    int seg0 = b * CAP;
    int n = min(bincur[b], CAP);
    if (t < 128) cnt[t] = 0;
    __syncthreads();
    for (int i = t; i < n; i += 256) atomicAdd(&cnt[binned[seg0 + i] >> 16], 1);
    __syncthreads();
    int v = (t < 128) ? cnt[t] : 0;
    if (t < 128) tmp[t] = v;
    __syncthreads();
    int val = v;
    for (int d = 1; d < 128; d <<= 1) {
        int add = (t >= d && t < 128) ? tmp[t - d] : 0;
        __syncthreads();
        if (t < 128) { val += add; tmp[t] = val; }
        __syncthreads();
    }
    if (t < 128) {
        int excl = val - v;
        cur[t] = excl;
        int node = n0 + t;
        if (node < N_NODES) {
            off[node] = seg0 + excl;
            deg[node] = (unsigned short)v;
        }
    }
    __syncthreads();
    for (int i = t; i < n; i += 256) {
        int w = binned[seg0 + i];
        int p = atomicAdd(&cur[w >> 16], 1);
        buf[p] = w & 0xFFFF;
    }
    __syncthreads();
    for (int i = t; i < n; i += 256) esrc[seg0 + i] = buf[i];   // coalesced
}

// ---------------- pre1: p = x@w1l (fp16), q = x@w1r + b1 (fp32) ----------------
__global__ __launch_bounds__(512) void k_pre1(const float* __restrict__ x,
                                              const float* __restrict__ wl,
                                              const float* __restrict__ wr,
                                              const float* __restrict__ b,
                                              __half* __restrict__ ph,
                                              float* __restrict__ q) {
    __shared__ float sx[64 * LSTRIDE];
    int t = threadIdx.x;
    int g0 = blockIdx.x * 128;
#pragma unroll
    for (int i = 0; i < 4; ++i) {
        int f = t + i * 512;
        int nd = f >> 4, cq = f & 15;
        int gn = g0 + nd;
        float4 v = (gn < N_NODES) ? ((const float4*)x)[(size_t)gn * 16 + cq]
                                  : make_float4(0.f, 0.f, 0.f, 0.f);
        sx[(cq * 4 + 0) * LSTRIDE + nd] = v.x;
        sx[(cq * 4 + 1) * LSTRIDE + nd] = v.y;
        sx[(cq * 4 + 2) * LSTRIDE + nd] = v.z;
        sx[(cq * 4 + 3) * LSTRIDE + nd] = v.w;
    }
    __syncthreads();
    int role = __builtin_amdgcn_readfirstlane(t >> 7);
    int wsel = role >> 1;
    int c0 = (role & 1) * 32;
    int ln = t & 127;
    int node = g0 + ln;
    const float* __restrict__ wm = wsel ? wr : wl;
    float acc[32];
    if (wsel) {
#pragma unroll
        for (int c = 0; c < 32; ++c) acc[c] = b[c0 + c];
    } else {
#pragma unroll
        for (int c = 0; c < 32; ++c) acc[c] = 0.f;
    }
#pragma unroll
    for (int k = 0; k < 64; ++k) {
        float xk = sx[k * LSTRIDE + ln];
#pragma unroll
        for (int c = 0; c < 32; ++c)
            acc[c] = fmaf(xk, wm[k * 64 + c0 + c], acc[c]);
    }
    if (node >= N_NODES) return;
    if (wsel == 0) {
        alignas(16) __half2 hv[16];
#pragma unroll
        for (int i = 0; i < 16; ++i)
            hv[i] = __floats2half2_rn(acc[2 * i], acc[2 * i + 1]);
        float4* op = (float4*)(ph + (size_t)node * 64 + c0);
#pragma unroll
        for (int i = 0; i < 4; ++i) op[i] = ((float4*)hv)[i];
    } else {
        float4* op = (float4*)(q + (size_t)node * 64 + c0);
#pragma unroll
        for (int i = 0; i < 8; ++i)
            op[i] = make_float4(acc[4 * i], acc[4 * i + 1], acc[4 * i + 2], acc[4 * i + 3]);
    }
}

// dequant-accumulate 16B of halfs into 8 fp32 accs
__device__ __forceinline__ void acc8(float* a, float4 rv) {
    const __half2* hp = (const __half2*)&rv;
    float2 f0 = __half22float2(hp[0]), f1 = __half22float2(hp[1]);
    float2 f2 = __half22float2(hp[2]), f3 = __half22float2(hp[3]);
    a[0] += f0.x; a[1] += f0.y; a[2] += f1.x; a[3] += f1.y;
    a[4] += f2.x; a[5] += f2.y; a[6] += f3.x; a[7] += f3.y;
}

// ---------------- agg1: h1 = relu(mean-gather(p) + q) ----------------
// half-wave (32 lanes) per node: eg = 0..3 edge slots, cg = 0..7 16B groups.
__global__ __launch_bounds__(256) void k_agg1(const int* __restrict__ off,
                                              const unsigned short* __restrict__ deg,
                                              const int* __restrict__ esrc,
                                              const __half* __restrict__ ph,
                                              const float* __restrict__ q,
                                              float* __restrict__ h1) {
    int wv = threadIdx.x >> 6, lane = threadIdx.x & 63;
    int h = lane >> 5, l32 = lane & 31;
    int node = blockIdx.x * 8 + wv * 2 + h;  // N % 8 == 0
    int eg = l32 >> 3;                        // 0..3
    int cg = l32 & 7;                         // 16B group: halfs cg*8..cg*8+7
    int s0 = off[node];
    int dv = deg[node];
    int s1 = s0 + dv;
    float a[8] = {0, 0, 0, 0, 0, 0, 0, 0};
    float c2[8] = {0, 0, 0, 0, 0, 0, 0, 0};
    for (int i = s0; i < s1; i += 8) {
        int i0 = i + eg, i1 = i + 4 + eg;
        if (i0 < s1) acc8(a,  *(const float4*)(ph + (size_t)esrc[i0] * 64 + (cg << 3)));
        if (i1 < s1) acc8(c2, *(const float4*)(ph + (size_t)esrc[i1] * 64 + (cg << 3)));
    }
#pragma unroll
    for (int j = 0; j < 8; ++j) a[j] += c2[j];
#pragma unroll
    for (int j = 0; j < 8; ++j) {
        a[j] += __shfl_xor(a[j], 8);
        a[j] += __shfl_xor(a[j], 16);
    }
    if (eg == 0) {
        float inv = 1.0f / fmaxf((float)dv, 1.0f);
        const float4* qp = (const float4*)(q + (size_t)node * 64 + (cg << 3));
        float4 q0 = qp[0], q1 = qp[1];
        float4 o0, o1;
        o0.x = fmaxf(fmaf(a[0], inv, q0.x), 0.f);
        o0.y = fmaxf(fmaf(a[1], inv, q0.y), 0.f);
        o0.z = fmaxf(fmaf(a[2], inv, q0.z), 0.f);
        o0.w = fmaxf(fmaf(a[3], inv, q0.w), 0.f);
        o1.x = fmaxf(fmaf(a[4], inv, q1.x), 0.f);
        o1.y = fmaxf(fmaf(a[5], inv, q1.y), 0.f);
        o1.z = fmaxf(fmaf(a[6], inv, q1.z), 0.f);
        o1.w = fmaxf(fmaf(a[7], inv, q1.w), 0.f);
        float4* op = (float4*)(h1 + (size_t)node * 64 + (cg << 3));
        op[0] = o0; op[1] = o1;
    }
}

// ---------------- pre2: z = h1@w2l (fp16), r = h1@w2r + b2 (fp32) ----------------
__global__ __launch_bounds__(256) void k_pre2(const float* __restrict__ h1,
                                              const float* __restrict__ w2l,
                                              const float* __restrict__ w2r,
                                              const float* __restrict__ b2,
                                              __half* __restrict__ zh,
                                              float* __restrict__ r) {
    __shared__ float sx[64 * LSTRIDE];
    int t = threadIdx.x;
    int g0 = blockIdx.x * 128;
#pragma unroll
    for (int i = 0; i < 8; ++i) {
        int f = t + i * 256;
        int nd = f >> 4, cq = f & 15;
        int gn = g0 + nd;
        float4 v = (gn < N_NODES) ? ((const float4*)h1)[(size_t)gn * 16 + cq]
                                  : make_float4(0.f, 0.f, 0.f, 0.f);
        sx[(cq * 4 + 0) * LSTRIDE + nd] = v.x;
        sx[(cq * 4 + 1) * LSTRIDE + nd] = v.y;
        sx[(cq * 4 + 2) * LSTRIDE + nd] = v.z;
        sx[(cq * 4 + 3) * LSTRIDE + nd] = v.w;
    }
    __syncthreads();
    int role = __builtin_amdgcn_readfirstlane(t >> 7);
    int ln = t & 127;
    int node = g0 + ln;
    const float* __restrict__ wm = role ? w2r : w2l;
    float acc[32];
    if (role) {
#pragma unroll
        for (int c = 0; c < 32; ++c) acc[c] = b2[c];
    } else {
#pragma unroll
        for (int c = 0; c < 32; ++c) acc[c] = 0.f;
    }
#pragma unroll
    for (int k = 0; k < 64; ++k) {
        float xk = sx[k * LSTRIDE + ln];
#pragma unroll
        for (int c = 0; c < 32; ++c)
            acc[c] = fmaf(xk, wm[k * 32 + c], acc[c]);
    }
    if (node >= N_NODES) return;
    if (role == 0) {
        alignas(16) __half2 hv[16];
#pragma unroll
        for (int i = 0; i < 16; ++i)
            hv[i] = __floats2half2_rn(acc[2 * i], acc[2 * i + 1]);
        float4* op = (float4*)(zh + (size_t)node * 32);
#pragma unroll
        for (int i = 0; i < 4; ++i) op[i] = ((float4*)hv)[i];
    } else {
        float4* op = (float4*)(r + (size_t)node * 32);
#pragma unroll
        for (int i = 0; i < 8; ++i)
            op[i] = make_float4(acc[4 * i], acc[4 * i + 1], acc[4 * i + 2], acc[4 * i + 3]);
    }
}

// ---------------- agg2 + classifier fused ----------------
// quarter-wave (16 lanes) per node; block = 16 nodes; h2 stays in LDS.
__global__ __launch_bounds__(256) void k_agg2cls(const int* __restrict__ off,
                                                 const unsigned short* __restrict__ deg,
                                                 const int* __restrict__ esrc,
                                                 const __half* __restrict__ zh,
                                                 const float* __restrict__ r,
                                                 const float* __restrict__ wc1,
                                                 const float* __restrict__ bc1,
                                                 const float* __restrict__ wc2,
                                                 const float* __restrict__ bc2,
                                                 float* __restrict__ out) {
    __shared__ float sh2[16 * 33];    // [node][ch], stride 33
    __shared__ float sh3[16 * 17];    // [node][j],  stride 17
    __shared__ float swc1[512];
    __shared__ float sbc1[16];
    __shared__ float swc2[32];
    __shared__ float sbc2[2];
    int t = threadIdx.x;
    swc1[t] = wc1[t];
    swc1[t + 256] = wc1[t + 256];
    if (t < 16) sbc1[t] = bc1[t];
    if (t < 32) swc2[t] = wc2[t];
    if (t < 2)  sbc2[t] = bc2[t];

    int lane = t & 63;
    int l16 = lane & 15;
    int nl = (t >> 4) & 15;                  // node-local 0..15
    int node = blockIdx.x * 16 + nl;         // N % 16 == 0
    int eg = l16 >> 2;                        // 0..3
    int cg = l16 & 3;                         // 16B group
    int s0 = off[node];
    int dv = deg[node];
    int s1 = s0 + dv;
    float a[8] = {0, 0, 0, 0, 0, 0, 0, 0};
    float c2[8] = {0, 0, 0, 0, 0, 0, 0, 0};
    for (int i = s0; i < s1; i += 8) {
        int i0 = i + eg, i1 = i + 4 + eg;
        if (i0 < s1) acc8(a,  *(const float4*)(zh + (size_t)esrc[i0] * 32 + (cg << 3)));
        if (i1 < s1) acc8(c2, *(const float4*)(zh + (size_t)esrc[i1] * 32 + (cg << 3)));
    }
#pragma unroll
    for (int j = 0; j < 8; ++j) a[j] += c2[j];
#pragma unroll
    for (int j = 0; j < 8; ++j) {
        a[j] += __shfl_xor(a[j], 4);
        a[j] += __shfl_xor(a[j], 8);
    }
    if (eg == 0) {
        float inv = 1.0f / fmaxf((float)dv, 1.0f);
        const float4* rp = (const float4*)(r + (size_t)node * 32 + (cg << 3));
        float4 r0 = rp[0], r1 = rp[1];
        float* d = sh2 + nl * 33 + (cg << 3);
        d[0] = fmaxf(fmaf(a[0], inv, r0.x), 0.f);
        d[1] = fmaxf(fmaf(a[1], inv, r0.y), 0.f);
        d[2] = fmaxf(fmaf(a[2], inv, r0.z), 0.f);
        d[3] = fmaxf(fmaf(a[3], inv, r0.w), 0.f);
        d[4] = fmaxf(fmaf(a[4], inv, r1.x), 0.f);
        d[5] = fmaxf(fmaf(a[5], inv, r1.y), 0.f);
        d[6] = fmaxf(fmaf(a[6], inv, r1.z), 0.f);
        d[7] = fmaxf(fmaf(a[7], inv, r1.w), 0.f);
    }
    __syncthreads();
    int n = t >> 4, j = t & 15;
    float acc1 = sbc1[j];
#pragma unroll
    for (int k = 0; k < 32; ++k)
        acc1 = fmaf(sh2[n * 33 + k], swc1[k * 16 + j], acc1);
    sh3[n * 17 + j] = fmaxf(acc1, 0.f);
    __syncthreads();
    if (t < 16) {
        int nn = t;
        float o0 = sbc2[0], o1 = sbc2[1];
#pragma unroll
        for (int k = 0; k < 16; ++k) {
            float h3k = sh3[nn * 17 + k];
            o0 = fmaf(h3k, swc2[k * 2 + 0], o0);
            o1 = fmaf(h3k, swc2[k * 2 + 1], o1);
        }
        int gnode = blockIdx.x * 16 + nn;
        *(float2*)(out + (size_t)gnode * 2) = make_float2(o0, o1);
    }
}

extern "C" void kernel_launch(void* const* d_in, const int* in_sizes, int n_in,
                              void* d_out, int out_size, void* d_ws, size_t ws_size,
                              hipStream_t stream) {
    const float* x   = (const float*)d_in[0];
    const int*   ei  = (const int*)d_in[1];
    const int*   src = ei;
    const int*   dst = ei + N_EDGES;
    const float* w1l = (const float*)d_in[2];
    const float* w1r = (const float*)d_in[3];
    const float* b1  = (const float*)d_in[4];
    const float* w2l = (const float*)d_in[5];
    const float* w2r = (const float*)d_in[6];
    const float* b2  = (const float*)d_in[7];
    const float* wc1 = (const float*)d_in[8];
    const float* bc1 = (const float*)d_in[9];
    const float* wc2 = (const float*)d_in[10];
    const float* bc2 = (const float*)d_in[11];
    float* out = (float*)d_out;

    // ws layout (4B units):
    //   bincur[400] | binned[NBINS*CAP] | esrc[NBINS*CAP] | off[N] | deg[N ushort]
    //   | h1[64N] | q[64N] (zh[16N]+r[32N] overlay) | ph[32N halfs]
    int*   wi     = (int*)d_ws;
    int*   bincur = wi;
    int*   binned = wi + 400;
    int*   esrc   = binned + (size_t)NBINS * CAP;
    int*   off    = esrc + (size_t)NBINS * CAP;
    unsigned short* deg = (unsigned short*)(off + N_NODES);
    float* h1     = (float*)(deg + N_NODES + (N_NODES & 1));
    float* q      = h1 + (size_t)64 * N_NODES;
    float* phf    = q + (size_t)64 * N_NODES;
    __half* ph    = (__half*)phf;
    __half* zh    = (__half*)q;                       // overlay: q dead after agg1
    float*  r     = q + (size_t)16 * N_NODES;

    // ---- bin-grouped edge list (fixed-capacity bins; no hist/scan passes) ----
    hipMemsetAsync(bincur, 0, 400 * sizeof(int), stream);
    k_binA<<<NBLK_E, 256, 0, stream>>>(src, dst, bincur, binned);
    k_binB<<<NBINS, 256, 0, stream>>>(bincur, binned, off, deg, esrc);

    // ---- layer 1 ----
    k_pre1<<<NTILE, 512, 0, stream>>>(x, w1l, w1r, b1, ph, q);
    k_agg1<<<N_NODES / 8, 256, 0, stream>>>(off, deg, esrc, ph, q, h1);

    // ---- layer 2 + classifier (fused) ----
    k_pre2<<<NTILE, 256, 0, stream>>>(h1, w2l, w2r, b2, zh, r);
    k_agg2cls<<<N_NODES / 16, 256, 0, stream>>>(off, deg, esrc, zh, r,
                                                wc1, bc1, wc2, bc2, out);
}

// Round 14
// 186.539 us; speedup vs baseline: 3.7282x; 1.0463x over previous
//
#include <hip/hip_runtime.h>
#include <hip/hip_fp16.h>

#define N_NODES 50000
#define N_EDGES 800000
#define NBINS   391          // ceil(50000/128), 128 dst nodes per bin
#define CAP     4096         // fixed per-bin capacity (mean 2048, sigma 45)
#define EPB     4096         // edges per block (binA)
#define NBLK_E  ((N_EDGES + EPB - 1) / EPB)
#define NTILE   391          // ceil(50000/128) node tiles for pre kernels
#define LSTRIDE 129          // LDS [ch][node] stride, conflict-free

// ---------------- pass A: LDS-staged bin scatter (fixed-capacity bins) ----------------
__global__ void k_binA(const int* __restrict__ src, const int* __restrict__ dst,
                       int* __restrict__ bincur, int* __restrict__ binned) {
    __shared__ int cnt[NBINS];
    __shared__ int sc[512];
    __shared__ int lpos[NBINS];
    __shared__ int base[NBINS];
    __shared__ int stage[EPB];
    __shared__ unsigned short sbin[EPB];
    int t = threadIdx.x;
    int blkbase = blockIdx.x * EPB;
    int nE = min(EPB, N_EDGES - blkbase);
    for (int i = t; i < NBINS; i += 256) cnt[i] = 0;
    __syncthreads();
    int sv[16], dv[16];
#pragma unroll
    for (int k = 0; k < 16; ++k) {
        int e = blkbase + t + k * 256;
        if (e < N_EDGES) {
            sv[k] = src[e];
            dv[k] = dst[e];
            atomicAdd(&cnt[dv[k] >> 7], 1);
        } else dv[k] = -1;
    }
    __syncthreads();
    sc[t]       = (t < NBINS) ? cnt[t] : 0;
    sc[t + 256] = (t + 256 < NBINS) ? cnt[t + 256] : 0;
    __syncthreads();
    for (int d = 1; d < 512; d <<= 1) {
        int s0 = t, s1 = t + 256;
        int n0 = sc[s0] + ((s0 >= d) ? sc[s0 - d] : 0);
        int n1 = sc[s1] + ((s1 >= d) ? sc[s1 - d] : 0);
        __syncthreads();
        sc[s0] = n0; sc[s1] = n1;
        __syncthreads();
    }
    for (int b = t; b < NBINS; b += 256) {
        int excl = sc[b] - cnt[b];
        lpos[b] = excl;
        sc[b] = excl;
        if (cnt[b] > 0) base[b] = b * CAP + atomicAdd(&bincur[b], cnt[b]);
    }
    __syncthreads();
#pragma unroll
    for (int k = 0; k < 16; ++k) {
        if (dv[k] >= 0) {
            int b = dv[k] >> 7;
            int p = atomicAdd(&lpos[b], 1);
            stage[p] = (sv[k] & 0xFFFF) | ((dv[k] & 127) << 16);
            sbin[p] = (unsigned short)b;
        }
    }
    __syncthreads();
    for (int i = t; i < nE; i += 256) {
        int b = sbin[i];
        int pos = base[b] + (i - sc[b]);
        if (pos < (b + 1) * CAP) binned[pos] = stage[i];   // 45-sigma guard
    }
}

// ---------------- fused: binB (counting sort) + pre1 (dual GEMM) ----------------
// blockIdx < NBINS: sort one bin (memory/LDS-bound). Else: pre1 tile (VALU-bound).
// The two populations overlap across CUs in a single dispatch.
__global__ __launch_bounds__(512) void k_binB_pre1(
        const int* __restrict__ bincur, int* __restrict__ binned,
        int* __restrict__ off, unsigned short* __restrict__ deg,
        int* __restrict__ esrc,
        const float* __restrict__ x,
        const float* __restrict__ wl, const float* __restrict__ wr,
        const float* __restrict__ b,
        __half* __restrict__ ph, float* __restrict__ q) {
    __shared__ float smem[64 * LSTRIDE];      // 33 KB, shared by both paths
    int t = threadIdx.x;
    int bb = blockIdx.x;
    if (bb < NBINS) {
        // ---- binB path (512 threads) ----
        int* buf = (int*)smem;                // CAP ints = 16 KB
        int* cnt = buf + CAP;                 // 128
        int* tmp = cnt + 128;                 // 128
        int* cur = tmp + 128;                 // 128
        int n0 = bb << 7;
        int seg0 = bb * CAP;
        int n = min(bincur[bb], CAP);
        if (t < 128) cnt[t] = 0;
        __syncthreads();
        for (int i = t; i < n; i += 512) atomicAdd(&cnt[binned[seg0 + i] >> 16], 1);
        __syncthreads();
        int v = (t < 128) ? cnt[t] : 0;
        if (t < 128) tmp[t] = v;
        __syncthreads();
        int val = v;
        for (int d = 1; d < 128; d <<= 1) {
            int add = (t >= d && t < 128) ? tmp[t - d] : 0;
            __syncthreads();
            if (t < 128) { val += add; tmp[t] = val; }
            __syncthreads();
        }
        if (t < 128) {
            int excl = val - v;
            cur[t] = excl;
            int node = n0 + t;
            if (node < N_NODES) {
                off[node] = seg0 + excl;
                deg[node] = (unsigned short)v;
            }
        }
        __syncthreads();
        for (int i = t; i < n; i += 512) {
            int w = binned[seg0 + i];
            int p = atomicAdd(&cur[w >> 16], 1);
            buf[p] = w & 0xFFFF;
        }
        __syncthreads();
        for (int i = t; i < n; i += 512) esrc[seg0 + i] = buf[i];   // coalesced
        return;
    }
    // ---- pre1 path (512 threads = 4 roles x 128 nodes) ----
    float* sx = smem;
    int g0 = (bb - NBINS) * 128;
#pragma unroll
    for (int i = 0; i < 4; ++i) {
        int f = t + i * 512;
        int nd = f >> 4, cq = f & 15;
        int gn = g0 + nd;
        float4 v = (gn < N_NODES) ? ((const float4*)x)[(size_t)gn * 16 + cq]
                                  : make_float4(0.f, 0.f, 0.f, 0.f);
        sx[(cq * 4 + 0) * LSTRIDE + nd] = v.x;
        sx[(cq * 4 + 1) * LSTRIDE + nd] = v.y;
        sx[(cq * 4 + 2) * LSTRIDE + nd] = v.z;
        sx[(cq * 4 + 3) * LSTRIDE + nd] = v.w;
    }
    __syncthreads();
    int role = __builtin_amdgcn_readfirstlane(t >> 7);
    int wsel = role >> 1;
    int c0 = (role & 1) * 32;
    int ln = t & 127;
    int node = g0 + ln;
    const float* __restrict__ wm = wsel ? wr : wl;
    float acc[32];
    if (wsel) {
#pragma unroll
        for (int c = 0; c < 32; ++c) acc[c] = b[c0 + c];
    } else {
#pragma unroll
        for (int c = 0; c < 32; ++c) acc[c] = 0.f;
    }
#pragma unroll
    for (int k = 0; k < 64; ++k) {
        float xk = sx[k * LSTRIDE + ln];
#pragma unroll
        for (int c = 0; c < 32; ++c)
            acc[c] = fmaf(xk, wm[k * 64 + c0 + c], acc[c]);
    }
    if (node >= N_NODES) return;
    if (wsel == 0) {
        alignas(16) __half2 hv[16];
#pragma unroll
        for (int i = 0; i < 16; ++i)
            hv[i] = __floats2half2_rn(acc[2 * i], acc[2 * i + 1]);
        float4* op = (float4*)(ph + (size_t)node * 64 + c0);
#pragma unroll
        for (int i = 0; i < 4; ++i) op[i] = ((float4*)hv)[i];
    } else {
        float4* op = (float4*)(q + (size_t)node * 64 + c0);
#pragma unroll
        for (int i = 0; i < 8; ++i)
            op[i] = make_float4(acc[4 * i], acc[4 * i + 1], acc[4 * i + 2], acc[4 * i + 3]);
    }
}

// dequant-accumulate 16B of halfs into 8 fp32 accs
__device__ __forceinline__ void acc8(float* a, float4 rv) {
    const __half2* hp = (const __half2*)&rv;
    float2 f0 = __half22float2(hp[0]), f1 = __half22float2(hp[1]);
    float2 f2 = __half22float2(hp[2]), f3 = __half22float2(hp[3]);
    a[0] += f0.x; a[1] += f0.y; a[2] += f1.x; a[3] += f1.y;
    a[4] += f2.x; a[5] += f2.y; a[6] += f3.x; a[7] += f3.y;
}

// ---------------- agg1: h1 = relu(mean-gather(p) + q) ----------------
// half-wave per node, 4 independent gather chains (16 edges/iter = avg node).
__global__ __launch_bounds__(256) void k_agg1(const int* __restrict__ off,
                                              const unsigned short* __restrict__ deg,
                                              const int* __restrict__ esrc,
                                              const __half* __restrict__ ph,
                                              const float* __restrict__ q,
                                              float* __restrict__ h1) {
    int wv = threadIdx.x >> 6, lane = threadIdx.x & 63;
    int h = lane >> 5, l32 = lane & 31;
    int node = blockIdx.x * 8 + wv * 2 + h;  // N % 8 == 0
    int eg = l32 >> 3;                        // 0..3
    int cg = l32 & 7;                         // 16B group
    int s0 = off[node];
    int dv = deg[node];
    int s1 = s0 + dv;
    float a0[8] = {0,0,0,0,0,0,0,0}, a1[8] = {0,0,0,0,0,0,0,0};
    float a2[8] = {0,0,0,0,0,0,0,0}, a3[8] = {0,0,0,0,0,0,0,0};
    for (int i = s0; i < s1; i += 16) {
        int i0 = i + eg, i1 = i + 4 + eg, i2 = i + 8 + eg, i3 = i + 12 + eg;
        if (i0 < s1) acc8(a0, *(const float4*)(ph + (size_t)esrc[i0] * 64 + (cg << 3)));
        if (i1 < s1) acc8(a1, *(const float4*)(ph + (size_t)esrc[i1] * 64 + (cg << 3)));
        if (i2 < s1) acc8(a2, *(const float4*)(ph + (size_t)esrc[i2] * 64 + (cg << 3)));
        if (i3 < s1) acc8(a3, *(const float4*)(ph + (size_t)esrc[i3] * 64 + (cg << 3)));
    }
#pragma unroll
    for (int j = 0; j < 8; ++j) a0[j] += a1[j] + (a2[j] + a3[j]);
#pragma unroll
    for (int j = 0; j < 8; ++j) {
        a0[j] += __shfl_xor(a0[j], 8);
        a0[j] += __shfl_xor(a0[j], 16);
    }
    if (eg == 0) {
        float inv = 1.0f / fmaxf((float)dv, 1.0f);
        const float4* qp = (const float4*)(q + (size_t)node * 64 + (cg << 3));
        float4 q0 = qp[0], q1 = qp[1];
        float4 o0, o1;
        o0.x = fmaxf(fmaf(a0[0], inv, q0.x), 0.f);
        o0.y = fmaxf(fmaf(a0[1], inv, q0.y), 0.f);
        o0.z = fmaxf(fmaf(a0[2], inv, q0.z), 0.f);
        o0.w = fmaxf(fmaf(a0[3], inv, q0.w), 0.f);
        o1.x = fmaxf(fmaf(a0[4], inv, q1.x), 0.f);
        o1.y = fmaxf(fmaf(a0[5], inv, q1.y), 0.f);
        o1.z = fmaxf(fmaf(a0[6], inv, q1.z), 0.f);
        o1.w = fmaxf(fmaf(a0[7], inv, q1.w), 0.f);
        float4* op = (float4*)(h1 + (size_t)node * 64 + (cg << 3));
        op[0] = o0; op[1] = o1;
    }
}

// ---------------- pre2: z = h1@w2l (fp16), r = h1@w2r + b2 (fp32) ----------------
__global__ __launch_bounds__(256) void k_pre2(const float* __restrict__ h1,
                                              const float* __restrict__ w2l,
                                              const float* __restrict__ w2r,
                                              const float* __restrict__ b2,
                                              __half* __restrict__ zh,
                                              float* __restrict__ r) {
    __shared__ float sx[64 * LSTRIDE];
    int t = threadIdx.x;
    int g0 = blockIdx.x * 128;
#pragma unroll
    for (int i = 0; i < 8; ++i) {
        int f = t + i * 256;
        int nd = f >> 4, cq = f & 15;
        int gn = g0 + nd;
        float4 v = (gn < N_NODES) ? ((const float4*)h1)[(size_t)gn * 16 + cq]
                                  : make_float4(0.f, 0.f, 0.f, 0.f);
        sx[(cq * 4 + 0) * LSTRIDE + nd] = v.x;
        sx[(cq * 4 + 1) * LSTRIDE + nd] = v.y;
        sx[(cq * 4 + 2) * LSTRIDE + nd] = v.z;
        sx[(cq * 4 + 3) * LSTRIDE + nd] = v.w;
    }
    __syncthreads();
    int role = __builtin_amdgcn_readfirstlane(t >> 7);
    int ln = t & 127;
    int node = g0 + ln;
    const float* __restrict__ wm = role ? w2r : w2l;
    float acc[32];
    if (role) {
#pragma unroll
        for (int c = 0; c < 32; ++c) acc[c] = b2[c];
    } else {
#pragma unroll
        for (int c = 0; c < 32; ++c) acc[c] = 0.f;
    }
#pragma unroll
    for (int k = 0; k < 64; ++k) {
        float xk = sx[k * LSTRIDE + ln];
#pragma unroll
        for (int c = 0; c < 32; ++c)
            acc[c] = fmaf(xk, wm[k * 32 + c], acc[c]);
    }
    if (node >= N_NODES) return;
    if (role == 0) {
        alignas(16) __half2 hv[16];
#pragma unroll
        for (int i = 0; i < 16; ++i)
            hv[i] = __floats2half2_rn(acc[2 * i], acc[2 * i + 1]);
        float4* op = (float4*)(zh + (size_t)node * 32);
#pragma unroll
        for (int i = 0; i < 4; ++i) op[i] = ((float4*)hv)[i];
    } else {
        float4* op = (float4*)(r + (size_t)node * 32);
#pragma unroll
        for (int i = 0; i < 8; ++i)
            op[i] = make_float4(acc[4 * i], acc[4 * i + 1], acc[4 * i + 2], acc[4 * i + 3]);
    }
}

// ---------------- agg2 + classifier fused ----------------
// quarter-wave per node, 4 gather chains (16 edges/iter); block = 16 nodes.
__global__ __launch_bounds__(256) void k_agg2cls(const int* __restrict__ off,
                                                 const unsigned short* __restrict__ deg,
                                                 const int* __restrict__ esrc,
                                                 const __half* __restrict__ zh,
                                                 const float* __restrict__ r,
                                                 const float* __restrict__ wc1,
                                                 const float* __restrict__ bc1,
                                                 const float* __restrict__ wc2,
                                                 const float* __restrict__ bc2,
                                                 float* __restrict__ out) {
    __shared__ float sh2[16 * 33];
    __shared__ float sh3[16 * 17];
    __shared__ float swc1[512];
    __shared__ float sbc1[16];
    __shared__ float swc2[32];
    __shared__ float sbc2[2];
    int t = threadIdx.x;
    swc1[t] = wc1[t];
    swc1[t + 256] = wc1[t + 256];
    if (t < 16) sbc1[t] = bc1[t];
    if (t < 32) swc2[t] = wc2[t];
    if (t < 2)  sbc2[t] = bc2[t];

    int lane = t & 63;
    int l16 = lane & 15;
    int nl = (t >> 4) & 15;
    int node = blockIdx.x * 16 + nl;         // N % 16 == 0
    int eg = l16 >> 2;                        // 0..3
    int cg = l16 & 3;                         // 16B group
    int s0 = off[node];
    int dv = deg[node];
    int s1 = s0 + dv;
    float a0[8] = {0,0,0,0,0,0,0,0}, a1[8] = {0,0,0,0,0,0,0,0};
    float a2[8] = {0,0,0,0,0,0,0,0}, a3[8] = {0,0,0,0,0,0,0,0};
    for (int i = s0; i < s1; i += 16) {
        int i0 = i + eg, i1 = i + 4 + eg, i2 = i + 8 + eg, i3 = i + 12 + eg;
        if (i0 < s1) acc8(a0, *(const float4*)(zh + (size_t)esrc[i0] * 32 + (cg << 3)));
        if (i1 < s1) acc8(a1, *(const float4*)(zh + (size_t)esrc[i1] * 32 + (cg << 3)));
        if (i2 < s1) acc8(a2, *(const float4*)(zh + (size_t)esrc[i2] * 32 + (cg << 3)));
        if (i3 < s1) acc8(a3, *(const float4*)(zh + (size_t)esrc[i3] * 32 + (cg << 3)));
    }
#pragma unroll
    for (int j = 0; j < 8; ++j) a0[j] += a1[j] + (a2[j] + a3[j]);
#pragma unroll
    for (int j = 0; j < 8; ++j) {
        a0[j] += __shfl_xor(a0[j], 4);
        a0[j] += __shfl_xor(a0[j], 8);
    }
    if (eg == 0) {
        float inv = 1.0f / fmaxf((float)dv, 1.0f);
        const float4* rp = (const float4*)(r + (size_t)node * 32 + (cg << 3));
        float4 r0 = rp[0], r1 = rp[1];
        float* d = sh2 + nl * 33 + (cg << 3);
        d[0] = fmaxf(fmaf(a0[0], inv, r0.x), 0.f);
        d[1] = fmaxf(fmaf(a0[1], inv, r0.y), 0.f);
        d[2] = fmaxf(fmaf(a0[2], inv, r0.z), 0.f);
        d[3] = fmaxf(fmaf(a0[3], inv, r0.w), 0.f);
        d[4] = fmaxf(fmaf(a0[4], inv, r1.x), 0.f);
        d[5] = fmaxf(fmaf(a0[5], inv, r1.y), 0.f);
        d[6] = fmaxf(fmaf(a0[6], inv, r1.z), 0.f);
        d[7] = fmaxf(fmaf(a0[7], inv, r1.w), 0.f);
    }
    __syncthreads();
    int n = t >> 4, j = t & 15;
    float acc1 = sbc1[j];
#pragma unroll
    for (int k = 0; k < 32; ++k)
        acc1 = fmaf(sh2[n * 33 + k], swc1[k * 16 + j], acc1);
    sh3[n * 17 + j] = fmaxf(acc1, 0.f);
    __syncthreads();
    if (t < 16) {
        int nn = t;
        float o0 = sbc2[0], o1 = sbc2[1];
#pragma unroll
        for (int k = 0; k < 16; ++k) {
            float h3k = sh3[nn * 17 + k];
            o0 = fmaf(h3k, swc2[k * 2 + 0], o0);
            o1 = fmaf(h3k, swc2[k * 2 + 1], o1);
        }
        int gnode = blockIdx.x * 16 + nn;
        *(float2*)(out + (size_t)gnode * 2) = make_float2(o0, o1);
    }
}

extern "C" void kernel_launch(void* const* d_in, const int* in_sizes, int n_in,
                              void* d_out, int out_size, void* d_ws, size_t ws_size,
                              hipStream_t stream) {
    const float* x   = (const float*)d_in[0];
    const int*   ei  = (const int*)d_in[1];
    const int*   src = ei;
    const int*   dst = ei + N_EDGES;
    const float* w1l = (const float*)d_in[2];
    const float* w1r = (const float*)d_in[3];
    const float* b1  = (const float*)d_in[4];
    const float* w2l = (const float*)d_in[5];
    const float* w2r = (const float*)d_in[6];
    const float* b2  = (const float*)d_in[7];
    const float* wc1 = (const float*)d_in[8];
    const float* bc1 = (const float*)d_in[9];
    const float* wc2 = (const float*)d_in[10];
    const float* bc2 = (const float*)d_in[11];
    float* out = (float*)d_out;

    // ws layout (4B units):
    //   bincur[400] | binned[NBINS*CAP] | esrc[NBINS*CAP] | off[N] | deg[N ushort]
    //   | h1[64N] | q[64N] (zh[16N]+r[32N] overlay) | ph[32N halfs]
    int*   wi     = (int*)d_ws;
    int*   bincur = wi;
    int*   binned = wi + 400;
    int*   esrc   = binned + (size_t)NBINS * CAP;
    int*   off    = esrc + (size_t)NBINS * CAP;
    unsigned short* deg = (unsigned short*)(off + N_NODES);
    float* h1     = (float*)(deg + N_NODES + (N_NODES & 1));
    float* q      = h1 + (size_t)64 * N_NODES;
    float* phf    = q + (size_t)64 * N_NODES;
    __half* ph    = (__half*)phf;
    __half* zh    = (__half*)q;                       // overlay: q dead after agg1
    float*  r     = q + (size_t)16 * N_NODES;

    // ---- bin-grouped edge list (fixed-capacity bins) ----
    hipMemsetAsync(bincur, 0, 400 * sizeof(int), stream);
    k_binA<<<NBLK_E, 256, 0, stream>>>(src, dst, bincur, binned);

    // ---- binB + pre1 overlapped in one dispatch ----
    k_binB_pre1<<<NBINS + NTILE, 512, 0, stream>>>(bincur, binned, off, deg, esrc,
                                                   x, w1l, w1r, b1, ph, q);

    // ---- layer 1 aggregation ----
    k_agg1<<<N_NODES / 8, 256, 0, stream>>>(off, deg, esrc, ph, q, h1);

    // ---- layer 2 + classifier ----
    k_pre2<<<NTILE, 256, 0, stream>>>(h1, w2l, w2r, b2, zh, r);
    k_agg2cls<<<N_NODES / 16, 256, 0, stream>>>(off, deg, esrc, zh, r,
                                                wc1, bc1, wc2, bc2, out);
}

// Round 15
// 186.082 us; speedup vs baseline: 3.7373x; 1.0025x over previous
//
#include <hip/hip_runtime.h>
#include <hip/hip_fp16.h>

#define N_NODES 50000
#define N_EDGES 800000
#define NBINS   391          // ceil(50000/128), 128 dst nodes per bin
#define CAP     4096         // fixed per-bin capacity (mean 2048, sigma 45)
#define EPB     4096         // edges per block (binA)
#define NBLK_E  ((N_EDGES + EPB - 1) / EPB)
#define NTILE   391          // node tiles for pre1
#define LSTRIDE 129          // LDS [ch][node] stride, conflict-free

// ---------------- pass A: LDS-staged bin scatter (fixed-capacity bins, 512 thr) ----------------
__global__ __launch_bounds__(512) void k_binA(const int* __restrict__ src,
                                              const int* __restrict__ dst,
                                              int* __restrict__ bincur,
                                              int* __restrict__ binned) {
    __shared__ int cnt[NBINS];
    __shared__ int sc[512];
    __shared__ int lpos[NBINS];
    __shared__ int base[NBINS];
    __shared__ int stage[EPB];
    __shared__ unsigned short sbin[EPB];
    int t = threadIdx.x;
    int blkbase = blockIdx.x * EPB;
    int nE = min(EPB, N_EDGES - blkbase);
    for (int i = t; i < NBINS; i += 512) cnt[i] = 0;
    __syncthreads();
    int sv[8], dv[8];
#pragma unroll
    for (int k = 0; k < 8; ++k) {
        int e = blkbase + t + k * 512;
        if (e < N_EDGES) {
            sv[k] = src[e];
            dv[k] = dst[e];
            atomicAdd(&cnt[dv[k] >> 7], 1);
        } else dv[k] = -1;
    }
    __syncthreads();
    sc[t] = (t < NBINS) ? cnt[t] : 0;
    __syncthreads();
    for (int d = 1; d < 512; d <<= 1) {
        int add = (t >= d) ? sc[t - d] : 0;
        __syncthreads();
        sc[t] += add;
        __syncthreads();
    }
    for (int b = t; b < NBINS; b += 512) {
        int excl = sc[b] - cnt[b];
        lpos[b] = excl;
        sc[b] = excl;
        if (cnt[b] > 0) base[b] = b * CAP + atomicAdd(&bincur[b], cnt[b]);
    }
    __syncthreads();
#pragma unroll
    for (int k = 0; k < 8; ++k) {
        if (dv[k] >= 0) {
            int b = dv[k] >> 7;
            int p = atomicAdd(&lpos[b], 1);
            stage[p] = (sv[k] & 0xFFFF) | ((dv[k] & 127) << 16);
            sbin[p] = (unsigned short)b;
        }
    }
    __syncthreads();
    for (int i = t; i < nE; i += 512) {
        int b = sbin[i];
        int pos = base[b] + (i - sc[b]);
        if (pos < (b + 1) * CAP) binned[pos] = stage[i];   // 45-sigma guard
    }
}

// ---------------- fused: binB (counting sort) + pre1 (dual GEMM) ----------------
__global__ __launch_bounds__(512) void k_binB_pre1(
        const int* __restrict__ bincur, int* __restrict__ binned,
        int* __restrict__ off, unsigned short* __restrict__ deg,
        int* __restrict__ esrc,
        const float* __restrict__ x,
        const float* __restrict__ wl, const float* __restrict__ wr,
        const float* __restrict__ b,
        __half* __restrict__ ph, float* __restrict__ q) {
    __shared__ float smem[64 * LSTRIDE];
    int t = threadIdx.x;
    int bb = blockIdx.x;
    if (bb < NBINS) {
        int* buf = (int*)smem;
        int* cnt = buf + CAP;
        int* tmp = cnt + 128;
        int* cur = tmp + 128;
        int n0 = bb << 7;
        int seg0 = bb * CAP;
        int n = min(bincur[bb], CAP);
        if (t < 128) cnt[t] = 0;
        __syncthreads();
        for (int i = t; i < n; i += 512) atomicAdd(&cnt[binned[seg0 + i] >> 16], 1);
        __syncthreads();
        int v = (t < 128) ? cnt[t] : 0;
        if (t < 128) tmp[t] = v;
        __syncthreads();
        int val = v;
        for (int d = 1; d < 128; d <<= 1) {
            int add = (t >= d && t < 128) ? tmp[t - d] : 0;
            __syncthreads();
            if (t < 128) { val += add; tmp[t] = val; }
            __syncthreads();
        }
        if (t < 128) {
            int excl = val - v;
            cur[t] = excl;
            int node = n0 + t;
            if (node < N_NODES) {
                off[node] = seg0 + excl;
                deg[node] = (unsigned short)v;
            }
        }
        __syncthreads();
        for (int i = t; i < n; i += 512) {
            int w = binned[seg0 + i];
            int p = atomicAdd(&cur[w >> 16], 1);
            buf[p] = w & 0xFFFF;
        }
        __syncthreads();
        for (int i = t; i < n; i += 512) esrc[seg0 + i] = buf[i];
        return;
    }
    // ---- pre1 path ----
    float* sx = smem;
    int g0 = (bb - NBINS) * 128;
#pragma unroll
    for (int i = 0; i < 4; ++i) {
        int f = t + i * 512;
        int nd = f >> 4, cq = f & 15;
        int gn = g0 + nd;
        float4 v = (gn < N_NODES) ? ((const float4*)x)[(size_t)gn * 16 + cq]
                                  : make_float4(0.f, 0.f, 0.f, 0.f);
        sx[(cq * 4 + 0) * LSTRIDE + nd] = v.x;
        sx[(cq * 4 + 1) * LSTRIDE + nd] = v.y;
        sx[(cq * 4 + 2) * LSTRIDE + nd] = v.z;
        sx[(cq * 4 + 3) * LSTRIDE + nd] = v.w;
    }
    __syncthreads();
    int role = __builtin_amdgcn_readfirstlane(t >> 7);
    int wsel = role >> 1;
    int c0 = (role & 1) * 32;
    int ln = t & 127;
    int node = g0 + ln;
    const float* __restrict__ wm = wsel ? wr : wl;
    float acc[32];
    if (wsel) {
#pragma unroll
        for (int c = 0; c < 32; ++c) acc[c] = b[c0 + c];
    } else {
#pragma unroll
        for (int c = 0; c < 32; ++c) acc[c] = 0.f;
    }
#pragma unroll
    for (int k = 0; k < 64; ++k) {
        float xk = sx[k * LSTRIDE + ln];
#pragma unroll
        for (int c = 0; c < 32; ++c)
            acc[c] = fmaf(xk, wm[k * 64 + c0 + c], acc[c]);
    }
    if (node >= N_NODES) return;
    if (wsel == 0) {
        alignas(16) __half2 hv[16];
#pragma unroll
        for (int i = 0; i < 16; ++i)
            hv[i] = __floats2half2_rn(acc[2 * i], acc[2 * i + 1]);
        float4* op = (float4*)(ph + (size_t)node * 64 + c0);
#pragma unroll
        for (int i = 0; i < 4; ++i) op[i] = ((float4*)hv)[i];
    } else {
        float4* op = (float4*)(q + (size_t)node * 64 + c0);
#pragma unroll
        for (int i = 0; i < 8; ++i)
            op[i] = make_float4(acc[4 * i], acc[4 * i + 1], acc[4 * i + 2], acc[4 * i + 3]);
    }
}

// dequant-accumulate 16B of halfs into 8 fp32 accs
__device__ __forceinline__ void acc8(float* a, float4 rv) {
    const __half2* hp = (const __half2*)&rv;
    float2 f0 = __half22float2(hp[0]), f1 = __half22float2(hp[1]);
    float2 f2 = __half22float2(hp[2]), f3 = __half22float2(hp[3]);
    a[0] += f0.x; a[1] += f0.y; a[2] += f1.x; a[3] += f1.y;
    a[4] += f2.x; a[5] += f2.y; a[6] += f3.x; a[7] += f3.y;
}

// ---------------- fused agg1 + pre2: one block per 128-node bin ----------------
// Phase 1 (gather): 32 half-waves x 4 passes; relu(h1) row -> LDS [ch][node] tile.
// Phase 2 (GEMM): pre2 structure (wave-uniform SGPR weights) on the LDS tile;
// h1 never touches global memory.
__global__ __launch_bounds__(1024) void k_agg1_pre2(
        const int* __restrict__ off, const unsigned short* __restrict__ deg,
        const int* __restrict__ esrc,
        const __half* __restrict__ ph, const float* __restrict__ q,
        const float* __restrict__ w2l, const float* __restrict__ w2r,
        const float* __restrict__ b2,
        __half* __restrict__ zh, float* __restrict__ r) {
    __shared__ float sx[64 * LSTRIDE];    // 33 KB h1 tile
    int t = threadIdx.x;
    int n0 = blockIdx.x << 7;
    int half = t >> 5;                    // 0..31 half-wave id
    int l32 = t & 31;
    int eg = l32 >> 3;                    // 0..3 edge slots
    int cg = l32 & 7;                     // 16B channel group
    for (int p = 0; p < 4; ++p) {
        int nl = half + 32 * p;           // 0..127
        int node = n0 + nl;
        if (node < N_NODES) {
            int s0 = off[node];
            int dv = deg[node];
            int s1 = s0 + dv;
            float a0[8] = {0,0,0,0,0,0,0,0}, a1[8] = {0,0,0,0,0,0,0,0};
            float a2[8] = {0,0,0,0,0,0,0,0}, a3[8] = {0,0,0,0,0,0,0,0};
            for (int i = s0; i < s1; i += 16) {
                int i0 = i + eg, i1 = i + 4 + eg, i2 = i + 8 + eg, i3 = i + 12 + eg;
                if (i0 < s1) acc8(a0, *(const float4*)(ph + (size_t)esrc[i0] * 64 + (cg << 3)));
                if (i1 < s1) acc8(a1, *(const float4*)(ph + (size_t)esrc[i1] * 64 + (cg << 3)));
                if (i2 < s1) acc8(a2, *(const float4*)(ph + (size_t)esrc[i2] * 64 + (cg << 3)));
                if (i3 < s1) acc8(a3, *(const float4*)(ph + (size_t)esrc[i3] * 64 + (cg << 3)));
            }
#pragma unroll
            for (int j = 0; j < 8; ++j) a0[j] += a1[j] + (a2[j] + a3[j]);
#pragma unroll
            for (int j = 0; j < 8; ++j) {
                a0[j] += __shfl_xor(a0[j], 8);
                a0[j] += __shfl_xor(a0[j], 16);
            }
            if (eg == 0) {
                float inv = 1.0f / fmaxf((float)dv, 1.0f);
                const float4* qp = (const float4*)(q + (size_t)node * 64 + (cg << 3));
                float4 q0 = qp[0], q1 = qp[1];
                float* d = sx + (cg << 3) * LSTRIDE + nl;
                d[0 * LSTRIDE] = fmaxf(fmaf(a0[0], inv, q0.x), 0.f);
                d[1 * LSTRIDE] = fmaxf(fmaf(a0[1], inv, q0.y), 0.f);
                d[2 * LSTRIDE] = fmaxf(fmaf(a0[2], inv, q0.z), 0.f);
                d[3 * LSTRIDE] = fmaxf(fmaf(a0[3], inv, q0.w), 0.f);
                d[4 * LSTRIDE] = fmaxf(fmaf(a0[4], inv, q1.x), 0.f);
                d[5 * LSTRIDE] = fmaxf(fmaf(a0[5], inv, q1.y), 0.f);
                d[6 * LSTRIDE] = fmaxf(fmaf(a0[6], inv, q1.z), 0.f);
                d[7 * LSTRIDE] = fmaxf(fmaf(a0[7], inv, q1.w), 0.f);
            }
        }
    }
    __syncthreads();
    // ---- GEMM phase: 8 groups of 128 threads = (role, c-group) x node ----
    int g = __builtin_amdgcn_readfirstlane(t >> 7);  // 0..7, wave-uniform
    int role = g & 1;                                 // 0: z (fp16), 1: r (fp32)
    int c0 = (g >> 1) * 8;                            // 0,8,16,24
    int ln = t & 127;
    int node = n0 + ln;
    const float* __restrict__ wm = role ? w2r : w2l;
    float acc[8];
    if (role) {
#pragma unroll
        for (int c = 0; c < 8; ++c) acc[c] = b2[c0 + c];
    } else {
#pragma unroll
        for (int c = 0; c < 8; ++c) acc[c] = 0.f;
    }
#pragma unroll
    for (int k = 0; k < 64; ++k) {
        float xk = sx[k * LSTRIDE + ln];
#pragma unroll
        for (int c = 0; c < 8; ++c)
            acc[c] = fmaf(xk, wm[k * 32 + c0 + c], acc[c]);
    }
    if (node >= N_NODES) return;
    if (role == 0) {
        alignas(16) __half2 hv[4];
#pragma unroll
        for (int i = 0; i < 4; ++i)
            hv[i] = __floats2half2_rn(acc[2 * i], acc[2 * i + 1]);
        *(float4*)(zh + (size_t)node * 32 + c0) = *(float4*)hv;
    } else {
        float4* op = (float4*)(r + (size_t)node * 32 + c0);
        op[0] = make_float4(acc[0], acc[1], acc[2], acc[3]);
        op[1] = make_float4(acc[4], acc[5], acc[6], acc[7]);
    }
}

// ---------------- agg2 + classifier fused ----------------
__global__ __launch_bounds__(256) void k_agg2cls(const int* __restrict__ off,
                                                 const unsigned short* __restrict__ deg,
                                                 const int* __restrict__ esrc,
                                                 const __half* __restrict__ zh,
                                                 const float* __restrict__ r,
                                                 const float* __restrict__ wc1,
                                                 const float* __restrict__ bc1,
                                                 const float* __restrict__ wc2,
                                                 const float* __restrict__ bc2,
                                                 float* __restrict__ out) {
    __shared__ float sh2[16 * 33];
    __shared__ float sh3[16 * 17];
    __shared__ float swc1[512];
    __shared__ float sbc1[16];
    __shared__ float swc2[32];
    __shared__ float sbc2[2];
    int t = threadIdx.x;
    swc1[t] = wc1[t];
    swc1[t + 256] = wc1[t + 256];
    if (t < 16) sbc1[t] = bc1[t];
    if (t < 32) swc2[t] = wc2[t];
    if (t < 2)  sbc2[t] = bc2[t];

    int lane = t & 63;
    int l16 = lane & 15;
    int nl = (t >> 4) & 15;
    int node = blockIdx.x * 16 + nl;         // N % 16 == 0
    int eg = l16 >> 2;
    int cg = l16 & 3;
    int s0 = off[node];
    int dv = deg[node];
    int s1 = s0 + dv;
    float a0[8] = {0,0,0,0,0,0,0,0}, a1[8] = {0,0,0,0,0,0,0,0};
    float a2[8] = {0,0,0,0,0,0,0,0}, a3[8] = {0,0,0,0,0,0,0,0};
    for (int i = s0; i < s1; i += 16) {
        int i0 = i + eg, i1 = i + 4 + eg, i2 = i + 8 + eg, i3 = i + 12 + eg;
        if (i0 < s1) acc8(a0, *(const float4*)(zh + (size_t)esrc[i0] * 32 + (cg << 3)));
        if (i1 < s1) acc8(a1, *(const float4*)(zh + (size_t)esrc[i1] * 32 + (cg << 3)));
        if (i2 < s1) acc8(a2, *(const float4*)(zh + (size_t)esrc[i2] * 32 + (cg << 3)));
        if (i3 < s1) acc8(a3, *(const float4*)(zh + (size_t)esrc[i3] * 32 + (cg << 3)));
    }
#pragma unroll
    for (int j = 0; j < 8; ++j) a0[j] += a1[j] + (a2[j] + a3[j]);
#pragma unroll
    for (int j = 0; j < 8; ++j) {
        a0[j] += __shfl_xor(a0[j], 4);
        a0[j] += __shfl_xor(a0[j], 8);
    }
    if (eg == 0) {
        float inv = 1.0f / fmaxf((float)dv, 1.0f);
        const float4* rp = (const float4*)(r + (size_t)node * 32 + (cg << 3));
        float4 r0 = rp[0], r1 = rp[1];
        float* d = sh2 + nl * 33 + (cg << 3);
        d[0] = fmaxf(fmaf(a0[0], inv, r0.x), 0.f);
        d[1] = fmaxf(fmaf(a0[1], inv, r0.y), 0.f);
        d[2] = fmaxf(fmaf(a0[2], inv, r0.z), 0.f);
        d[3] = fmaxf(fmaf(a0[3], inv, r0.w), 0.f);
        d[4] = fmaxf(fmaf(a0[4], inv, r1.x), 0.f);
        d[5] = fmaxf(fmaf(a0[5], inv, r1.y), 0.f);
        d[6] = fmaxf(fmaf(a0[6], inv, r1.z), 0.f);
        d[7] = fmaxf(fmaf(a0[7], inv, r1.w), 0.f);
    }
    __syncthreads();
    int n = t >> 4, j = t & 15;
    float acc1 = sbc1[j];
#pragma unroll
    for (int k = 0; k < 32; ++k)
        acc1 = fmaf(sh2[n * 33 + k], swc1[k * 16 + j], acc1);
    sh3[n * 17 + j] = fmaxf(acc1, 0.f);
    __syncthreads();
    if (t < 16) {
        int nn = t;
        float o0 = sbc2[0], o1 = sbc2[1];
#pragma unroll
        for (int k = 0; k < 16; ++k) {
            float h3k = sh3[nn * 17 + k];
            o0 = fmaf(h3k, swc2[k * 2 + 0], o0);
            o1 = fmaf(h3k, swc2[k * 2 + 1], o1);
        }
        int gnode = blockIdx.x * 16 + nn;
        *(float2*)(out + (size_t)gnode * 2) = make_float2(o0, o1);
    }
}

extern "C" void kernel_launch(void* const* d_in, const int* in_sizes, int n_in,
                              void* d_out, int out_size, void* d_ws, size_t ws_size,
                              hipStream_t stream) {
    const float* x   = (const float*)d_in[0];
    const int*   ei  = (const int*)d_in[1];
    const int*   src = ei;
    const int*   dst = ei + N_EDGES;
    const float* w1l = (const float*)d_in[2];
    const float* w1r = (const float*)d_in[3];
    const float* b1  = (const float*)d_in[4];
    const float* w2l = (const float*)d_in[5];
    const float* w2r = (const float*)d_in[6];
    const float* b2  = (const float*)d_in[7];
    const float* wc1 = (const float*)d_in[8];
    const float* bc1 = (const float*)d_in[9];
    const float* wc2 = (const float*)d_in[10];
    const float* bc2 = (const float*)d_in[11];
    float* out = (float*)d_out;

    // ws layout (4B units), all regions disjoint (no overlays):
    //   bincur[400] | binned[NBINS*CAP] | esrc[NBINS*CAP] | off[N] | deg[N ushort]
    //   | q[64N] | ph[64N halfs = 32N] | zh[32N halfs = 16N] | r[32N]
    int*   wi     = (int*)d_ws;
    int*   bincur = wi;
    int*   binned = wi + 400;
    int*   esrc   = binned + (size_t)NBINS * CAP;
    int*   off    = esrc + (size_t)NBINS * CAP;
    unsigned short* deg = (unsigned short*)(off + N_NODES);
    float* q      = (float*)(deg + N_NODES + (N_NODES & 1));
    float* phf    = q + (size_t)64 * N_NODES;
    __half* ph    = (__half*)phf;
    float* zhf    = phf + (size_t)32 * N_NODES;
    __half* zh    = (__half*)zhf;
    float* r      = zhf + (size_t)16 * N_NODES;

    // ---- bin-grouped edge list ----
    hipMemsetAsync(bincur, 0, 400 * sizeof(int), stream);
    k_binA<<<NBLK_E, 512, 0, stream>>>(src, dst, bincur, binned);

    // ---- binB + pre1 overlapped ----
    k_binB_pre1<<<NBINS + NTILE, 512, 0, stream>>>(bincur, binned, off, deg, esrc,
                                                   x, w1l, w1r, b1, ph, q);

    // ---- layer 1 aggregation + layer 2 pre-GEMM (fused, h1 stays in LDS) ----
    k_agg1_pre2<<<NBINS, 1024, 0, stream>>>(off, deg, esrc, ph, q,
                                            w2l, w2r, b2, zh, r);

    // ---- layer 2 aggregation + classifier ----
    k_agg2cls<<<N_NODES / 16, 256, 0, stream>>>(off, deg, esrc, zh, r,
                                                wc1, bc1, wc2, bc2, out);
}